// Round 14
// baseline (853.180 us; speedup 1.0000x reference)
//
#include <hip/hip_runtime.h>
#include <hip/hip_bf16.h>
#include <math.h>

// Sizes: B=2 T=32 C=3 H=W=64 P=8 -> N=64, D=512, L=2048, M=B*T*N=4096
#define MTOK 4096

typedef __bf16 bf16x8 __attribute__((ext_vector_type(8)));
typedef float f32x4 __attribute__((ext_vector_type(4)));

__device__ __forceinline__ ushort f2bf(float f){
  __hip_bfloat16 h = __float2bfloat16(f);
  return *reinterpret_cast<ushort*>(&h);
}
__device__ __forceinline__ float bf2f(ushort u){
  return __uint_as_float(((uint)u) << 16);
}
__device__ __forceinline__ void gload_lds16(const void* g, void* l){
  __builtin_amdgcn_global_load_lds((__attribute__((address_space(1))) void*)(void*)g,
                                   (__attribute__((address_space(3))) void*)l, 16, 0, 0);
}

__device__ __forceinline__ float blockReduceSum(float v, float* red){
  #pragma unroll
  for (int off = 32; off; off >>= 1) v += __shfl_down(v, off, 64);
  int lane = threadIdx.x & 63, wid = threadIdx.x >> 6;
  __syncthreads();
  if (lane == 0) red[wid] = v;
  __syncthreads();
  float r = 0.f;
  int nw = blockDim.x >> 6;
  for (int i = 0; i < nw; i++) r += red[i];
  return r;
}
__device__ __forceinline__ float rowMax16(float v){
  #pragma unroll
  for (int m = 8; m; m >>= 1) v = fmaxf(v, __shfl_xor(v, m, 64));
  return v;
}
__device__ __forceinline__ float rowSum16(float v){
  #pragma unroll
  for (int m = 8; m; m >>= 1) v += __shfl_xor(v, m, 64);
  return v;
}

// ---------------- weight f32 -> bf16 (per-matrix fallback) ----------------
__global__ __launch_bounds__(256) void cvt_w_kernel(
    const float* __restrict__ src, ushort* __restrict__ dst, int n)
{
  int i = (blockIdx.x * 256 + threadIdx.x) * 8;
  float4 a = *(const float4*)(src + i);
  float4 b = *(const float4*)(src + i + 4);
  uint4 o;
  o.x = (uint)f2bf(a.x) | ((uint)f2bf(a.y) << 16);
  o.y = (uint)f2bf(a.z) | ((uint)f2bf(a.w) << 16);
  o.z = (uint)f2bf(b.x) | ((uint)f2bf(b.y) << 16);
  o.w = (uint)f2bf(b.z) | ((uint)f2bf(b.w) << 16);
  *(uint4*)(dst + i) = o;
}

// ---------------- all weights -> bf16 arena (one dispatch) ----------------
#define OFF_PATCH 0u
#define OFF_SAIN  98304u
#define OFF_SAOUT 2457600u
#define OFF_KQV   3244032u
#define OFF_PROJ  7962624u
#define OFF_FC    9535488u
#define OFF_CPROJ 15826944u
#define W_TOTAL   22118400u
__global__ __launch_bounds__(256) void cvt_all_kernel(
    const float* __restrict__ pw, const float* __restrict__ sain,
    const float* __restrict__ saout, const float* __restrict__ kqv,
    const float* __restrict__ proj, const float* __restrict__ fc,
    const float* __restrict__ cproj, ushort* __restrict__ dst)
{
  int blk = blockIdx.x;
  const float* src; size_t off;
  if      (blk <    48){ src = pw;    off = OFF_PATCH; }
  else if (blk <  1200){ src = sain;  off = OFF_SAIN;  blk -= 48;   }
  else if (blk <  1584){ src = saout; off = OFF_SAOUT; blk -= 1200; }
  else if (blk <  3888){ src = kqv;   off = OFF_KQV;   blk -= 1584; }
  else if (blk <  4656){ src = proj;  off = OFF_PROJ;  blk -= 3888; }
  else if (blk <  7728){ src = fc;    off = OFF_FC;    blk -= 4656; }
  else                 { src = cproj; off = OFF_CPROJ; blk -= 7728; }
  size_t si = (size_t)blk*2048 + threadIdx.x*8;
  float4 a = *(const float4*)(src + si);
  float4 b = *(const float4*)(src + si + 4);
  uint4 o;
  o.x = (uint)f2bf(a.x) | ((uint)f2bf(a.y) << 16);
  o.y = (uint)f2bf(a.z) | ((uint)f2bf(a.w) << 16);
  o.z = (uint)f2bf(b.x) | ((uint)f2bf(b.y) << 16);
  o.w = (uint)f2bf(b.z) | ((uint)f2bf(b.w) << 16);
  *(uint4*)(dst + off + si) = o;
}

// ---------------- im2col: x -> patches [4096][192] bf16 ----------------
__global__ __launch_bounds__(256) void im2col_kernel(
    const float* __restrict__ x, ushort* __restrict__ Pm)
{
  int idx = blockIdx.x*256 + threadIdx.x;   // 0..98303
  int m = idx / 24, e8 = idx % 24;
  int b = m >> 11, t = (m >> 6) & 31, n = m & 63;
  int hn = n >> 3, wn = n & 7;
  int c = e8 >> 3, ph = e8 & 7;
  const float* src = x + (((size_t)(b*32 + t)*3 + c)*64 + hn*8 + ph)*64 + wn*8;
  float4 a = *(const float4*)src;
  float4 bq = *(const float4*)(src + 4);
  uint4 o;
  o.x = (uint)f2bf(a.x) | ((uint)f2bf(a.y) << 16);
  o.y = (uint)f2bf(a.z) | ((uint)f2bf(a.w) << 16);
  o.z = (uint)f2bf(bq.x) | ((uint)f2bf(bq.y) << 16);
  o.w = (uint)f2bf(bq.z) | ((uint)f2bf(bq.w) << 16);
  *(uint4*)(Pm + (size_t)m*192 + e8*8) = o;
}

// ---------------- tok LN + pos (wave per row, 4 rows/block) ----------------
__global__ __launch_bounds__(256) void ln_pos_kernel(
    const float* __restrict__ in, float* __restrict__ out,
    const float* __restrict__ g, const float* __restrict__ b,
    const float* __restrict__ spos, const float* __restrict__ tpos)
{
  int r = blockIdx.x*4 + (threadIdx.x >> 6);
  int lane = threadIdx.x & 63;
  int n = r & 63, t = (r >> 6) & 31;
  const float* row = in + (size_t)r*512 + lane*8;
  float4 v0 = *(const float4*)row;
  float4 v1 = *(const float4*)(row + 4);
  float s = v0.x+v0.y+v0.z+v0.w+v1.x+v1.y+v1.z+v1.w;
  float q = v0.x*v0.x+v0.y*v0.y+v0.z*v0.z+v0.w*v0.w+v1.x*v1.x+v1.y*v1.y+v1.z*v1.z+v1.w*v1.w;
  #pragma unroll
  for (int m = 1; m < 64; m <<= 1){ s += __shfl_xor(s, m, 64); q += __shfl_xor(q, m, 64); }
  float mu = s*(1.f/512.f);
  float inv = rsqrtf(q*(1.f/512.f) - mu*mu + 1e-5f);
  const float* gp = g + lane*8;
  const float* bp = b + lane*8;
  const float* sp = spos + n*512 + lane*8;
  const float* tp = tpos + t*512 + lane*8;
  float* op = out + (size_t)r*512 + lane*8;
  #pragma unroll
  for (int e = 0; e < 2; e++){
    float4 vv = e ? v1 : v0;
    float4 gg = *(const float4*)(gp + e*4);
    float4 bb = *(const float4*)(bp + e*4);
    float4 ss = *(const float4*)(sp + e*4);
    float4 tt = *(const float4*)(tp + e*4);
    float4 oo;
    oo.x = (vv.x-mu)*inv*gg.x + bb.x + ss.x + tt.x;
    oo.y = (vv.y-mu)*inv*gg.y + bb.y + ss.y + tt.y;
    oo.z = (vv.z-mu)*inv*gg.z + bb.z + ss.z + tt.z;
    oo.w = (vv.w-mu)*inv*gg.w + bb.w + ss.w + tt.w;
    *(float4*)(op + e*4) = oo;
  }
}

// ---------------- LayerNorm (D=512) fp32 in -> bf16 out (wave per row) ----------------
__global__ __launch_bounds__(256) void ln_bf16_kernel(
    const float* __restrict__ in, ushort* __restrict__ out,
    const float* __restrict__ g, const float* __restrict__ b)
{
  int r = blockIdx.x*4 + (threadIdx.x >> 6);
  int lane = threadIdx.x & 63;
  const float* row = in + (size_t)r*512 + lane*8;
  float4 v0 = *(const float4*)row;
  float4 v1 = *(const float4*)(row + 4);
  float s = v0.x+v0.y+v0.z+v0.w+v1.x+v1.y+v1.z+v1.w;
  float q = v0.x*v0.x+v0.y*v0.y+v0.z*v0.z+v0.w*v0.w+v1.x*v1.x+v1.y*v1.y+v1.z*v1.z+v1.w*v1.w;
  #pragma unroll
  for (int m = 1; m < 64; m <<= 1){ s += __shfl_xor(s, m, 64); q += __shfl_xor(q, m, 64); }
  float mu = s*(1.f/512.f);
  float inv = rsqrtf(q*(1.f/512.f) - mu*mu + 1e-5f);
  float4 g0 = *(const float4*)(g + lane*8);
  float4 g1 = *(const float4*)(g + lane*8 + 4);
  float4 b0 = *(const float4*)(b + lane*8);
  float4 b1 = *(const float4*)(b + lane*8 + 4);
  uint4 o;
  o.x = (uint)f2bf((v0.x-mu)*inv*g0.x + b0.x) | ((uint)f2bf((v0.y-mu)*inv*g0.y + b0.y) << 16);
  o.y = (uint)f2bf((v0.z-mu)*inv*g0.z + b0.z) | ((uint)f2bf((v0.w-mu)*inv*g0.w + b0.w) << 16);
  o.z = (uint)f2bf((v1.x-mu)*inv*g1.x + b1.x) | ((uint)f2bf((v1.y-mu)*inv*g1.y + b1.y) << 16);
  o.w = (uint)f2bf((v1.z-mu)*inv*g1.z + b1.z) | ((uint)f2bf((v1.w-mu)*inv*g1.w + b1.w) << 16);
  *(uint4*)(out + (size_t)r*512 + lane*8) = o;
}

// ---------------- MFMA GEMM v3 ----------------
// Both operands double-buffered via global_load_lds, 1 barrier/K-step.
// kstride = row stride of X and Wb (elements); K = reduction length handled here.
// blockIdx.z K-split: X/Wb advanced by z*zko elements, output by z*zyo bytes.
// bias may be null (partial-K mode).
template<int BM, int BN, bool GELU, bool BF16OUT>
__global__ __launch_bounds__(256) void gemm2_kernel(
    const ushort* __restrict__ X, const ushort* __restrict__ Wb,
    const float* __restrict__ bias, const float* __restrict__ res,
    void* __restrict__ Yv, int M, int Nn, int K, int kstride, int zko, size_t zyo)
{
  constexpr int WROWS = (BN == 128) ? 2 : 4;
  constexpr int WM = BM / WROWS;
  constexpr int FM = WM / 16;
  constexpr int FN = 4;
  __shared__ __attribute__((aligned(16))) char smem[2*(BM+BN)*128];
  char* Xs0 = smem;
  char* Ws0 = smem + BM*128;
  char* Xs1 = smem + (BM+BN)*128;
  char* Ws1 = Xs1 + BM*128;
  int tid = threadIdx.x, lane = tid & 63, wv = tid >> 6;
  int bm = blockIdx.y * BM, bn = blockIdx.x * BN;
  int z = blockIdx.z;
  X  += (size_t)z * zko;
  Wb += (size_t)z * zko;
  char* Yb = (char*)Yv + (size_t)z * zyo;
  int wm, wn;
  if (BN == 128){ wm = (wv >> 1) * WM; wn = (wv & 1) * 64; }
  else          { wm = wv * WM;        wn = 0; }

  f32x4 acc[FM][FN];
  #pragma unroll
  for (int i = 0; i < FM; i++)
    #pragma unroll
    for (int j = 0; j < FN; j++){ f32x4 zz = {0.f,0.f,0.f,0.f}; acc[i][j] = zz; }

  int rowoff = wv*8 + (lane >> 3);
  int colsrc = ((lane & 7) ^ (lane >> 3)) * 16;

  auto stage = [&](char* Xd, char* Wd, int k0){
    #pragma unroll
    for (int i = 0; i < BM/32; i++){
      int row = i*32 + rowoff;
      gload_lds16((const char*)(X + (size_t)(bm + row)*kstride + k0) + colsrc,
                  Xd + (i*32 + wv*8)*128);
    }
    #pragma unroll
    for (int i = 0; i < BN/32; i++){
      int row = i*32 + rowoff;
      gload_lds16((const char*)(Wb + (size_t)(bn + row)*kstride + k0) + colsrc,
                  Wd + (i*32 + wv*8)*128);
    }
  };

  stage(Xs0, Ws0, 0);
  __syncthreads();
  int nt = K >> 6;
  for (int t = 0; t < nt; t++){
    char* Xc = (t & 1) ? Xs1 : Xs0;
    char* Wc = (t & 1) ? Ws1 : Ws0;
    if (t + 1 < nt) stage((t & 1) ? Xs0 : Xs1, (t & 1) ? Ws0 : Ws1, (t+1)*64);
    #pragma unroll
    for (int kc = 0; kc < 2; kc++){
      bf16x8 a[FM], b[FN];
      #pragma unroll
      for (int f = 0; f < FM; f++){
        int ra = wm + f*16 + (lane & 15);
        a[f] = *(const bf16x8*)(Xc + ra*128 + ((kc*64 + (lane>>4)*16) ^ ((ra & 7) << 4)));
      }
      #pragma unroll
      for (int f = 0; f < FN; f++){
        int rb = wn + f*16 + (lane & 15);
        b[f] = *(const bf16x8*)(Wc + rb*128 + ((kc*64 + (lane>>4)*16) ^ ((rb & 7) << 4)));
      }
      #pragma unroll
      for (int i = 0; i < FM; i++)
        #pragma unroll
        for (int j = 0; j < FN; j++)
          acc[i][j] = __builtin_amdgcn_mfma_f32_16x16x32_bf16(a[i], b[j], acc[i][j], 0, 0, 0);
    }
    __syncthreads();
  }
  int col0 = lane & 15;
  float bv[FN];
  #pragma unroll
  for (int fn = 0; fn < FN; fn++) bv[fn] = bias ? bias[bn + wn + fn*16 + col0] : 0.f;
  #pragma unroll
  for (int fm = 0; fm < FM; fm++){
    #pragma unroll
    for (int r = 0; r < 4; r++){
      int m = bm + wm + fm*16 + (lane >> 4)*4 + r;
      #pragma unroll
      for (int fn = 0; fn < FN; fn++){
        int n = bn + wn + fn*16 + col0;
        float v = acc[fm][fn][r] + bv[fn];
        if (res) v += res[(size_t)m*Nn + n];
        if (GELU) v = 0.5f * v * (1.f + erff(v * 0.70710678118654752440f));
        if (BF16OUT) ((ushort*)Yb)[(size_t)m*Nn + n] = f2bf(v);
        else         ((float*) Yb)[(size_t)m*Nn + n] = v;
      }
    }
  }
}

// ---------------- cproj K-split merge: A += bias + Y0 + Y1 ----------------
__global__ __launch_bounds__(256) void cproj_merge_kernel(
    const float* __restrict__ Yp, const float* __restrict__ bias, float* __restrict__ A)
{
  int i = (blockIdx.x*256 + threadIdx.x) * 4;   // 2M elems / 4
  int n = i & 511;
  float4 y0 = *(const float4*)(Yp + i);
  float4 y1 = *(const float4*)(Yp + (size_t)MTOK*512 + i);
  float4 a  = *(const float4*)(A + i);
  float4 b4 = *(const float4*)(bias + n);
  float4 o;
  o.x = a.x + b4.x + y0.x + y1.x;
  o.y = a.y + b4.y + y0.y + y1.y;
  o.z = a.z + b4.z + y0.z + y1.z;
  o.w = a.w + b4.w + y0.w + y1.w;
  *(float4*)(A + i) = o;
}

// ---------------- spatial attention, bf16 MFMA (unchanged) ----------------
__global__ __launch_bounds__(256) void spatial_attn_mfma_kernel(
    const ushort* __restrict__ qkv, ushort* __restrict__ y)
{
  __shared__ __attribute__((aligned(16))) char Ks[64*256];
  __shared__ __attribute__((aligned(16))) char Vt[128*128];
  __shared__ __attribute__((aligned(16))) char Ps[64*128];
  int bt = blockIdx.x, h = blockIdx.y;
  int tid = threadIdx.x, lane = tid & 63, w = tid >> 6;
  const ushort* base = qkv + (size_t)bt*64*1536 + (size_t)h*128;
  const float scale = 0.08838834764831845f;

  int qrow = w*16 + (lane & 15);
  bf16x8 qa[4];
  #pragma unroll
  for (int kc = 0; kc < 4; kc++)
    qa[kc] = *(const bf16x8*)(base + (size_t)qrow*1536 + kc*32 + (lane>>4)*8);

  #pragma unroll
  for (int i = 0; i < 4; i++){
    int row = w*16 + i*4 + (lane >> 4);
    const char* src = (const char*)(base + (size_t)row*1536 + 512) + (((lane & 15) ^ (row & 15)) * 16);
    char* dst = Ks + (w*16 + i*4)*256;
    gload_lds16(src, dst);
  }
  {
    int vj = (tid & 31) * 2;
    int d0 = (tid >> 5) * 16;
    const ushort* v0p = base + (size_t)vj*1536 + 1024 + d0;
    const ushort* v1p = v0p + 1536;
    uint4 a0 = *(const uint4*)(v0p);
    uint4 a1 = *(const uint4*)(v0p + 8);
    uint4 b0 = *(const uint4*)(v1p);
    uint4 b1 = *(const uint4*)(v1p + 8);
    uint av[8] = {a0.x, a0.y, a0.z, a0.w, a1.x, a1.y, a1.z, a1.w};
    uint bv[8] = {b0.x, b0.y, b0.z, b0.w, b1.x, b1.y, b1.z, b1.w};
    int cb = 4 * (tid & 31);
    #pragma unroll
    for (int e = 0; e < 8; e++){
      int dl = d0 + e*2, dh = dl + 1;
      uint vlo = (av[e] & 0xffffu) | ((bv[e] & 0xffffu) << 16);
      uint vhi = (av[e] >> 16) | (bv[e] & 0xffff0000u);
      *(uint*)(Vt + dl*128 + (cb ^ ((dl & 7) << 4))) = vlo;
      *(uint*)(Vt + dh*128 + (cb ^ ((dh & 7) << 4))) = vhi;
    }
  }
  __syncthreads();

  f32x4 zero4 = {0.f,0.f,0.f,0.f};
  f32x4 accS[4];
  __builtin_amdgcn_s_setprio(1);
  #pragma unroll
  for (int jt = 0; jt < 4; jt++){
    accS[jt] = zero4;
    #pragma unroll
    for (int kc = 0; kc < 4; kc++){
      int krow = jt*16 + (lane & 15);
      bf16x8 kb = *(const bf16x8*)(Ks + krow*256 + ((kc*64 + (lane>>4)*16) ^ ((krow & 15) << 4)));
      accS[jt] = __builtin_amdgcn_mfma_f32_16x16x32_bf16(qa[kc], kb, accS[jt], 0, 0, 0);
    }
  }
  __builtin_amdgcn_s_setprio(0);
  float l_sum[4];
  #pragma unroll
  for (int r = 0; r < 4; r++){
    float mx = fmaxf(fmaxf(accS[0][r], accS[1][r]), fmaxf(accS[2][r], accS[3][r]));
    mx = rowMax16(mx);
    int prow = w*16 + (lane>>4)*4 + r;
    int swz = (prow & 7) << 4;
    char* pbase = Ps + prow*128;
    float ps = 0.f;
    #pragma unroll
    for (int jt = 0; jt < 4; jt++){
      float p = __expf((accS[jt][r] - mx) * scale);
      ushort pb = f2bf(p);
      *(ushort*)(pbase + ((2*(jt*16 + (lane & 15))) ^ swz)) = pb;
      ps += bf2f(pb);
    }
    l_sum[r] = rowSum16(ps);
  }
  bf16x8 pa[2];
  #pragma unroll
  for (int kc2 = 0; kc2 < 2; kc2++){
    int prow = w*16 + (lane & 15);
    pa[kc2] = *(const bf16x8*)(Ps + prow*128 + ((kc2*64 + (lane>>4)*16) ^ ((prow & 7) << 4)));
  }
  f32x4 o[8];
  __builtin_amdgcn_s_setprio(1);
  #pragma unroll
  for (int dt = 0; dt < 8; dt++){
    o[dt] = zero4;
    #pragma unroll
    for (int kc2 = 0; kc2 < 2; kc2++){
      int vrow = dt*16 + (lane & 15);
      bf16x8 vb = *(const bf16x8*)(Vt + vrow*128 + ((kc2*64 + (lane>>4)*16) ^ ((vrow & 7) << 4)));
      o[dt] = __builtin_amdgcn_mfma_f32_16x16x32_bf16(pa[kc2], vb, o[dt], 0, 0, 0);
    }
  }
  __builtin_amdgcn_s_setprio(0);
  #pragma unroll
  for (int r = 0; r < 4; r++){
    float invl = 1.f / l_sum[r];
    int token = bt*64 + w*16 + (lane>>4)*4 + r;
    ushort* yrow = y + (size_t)token*512 + h*128;
    #pragma unroll
    for (int dt = 0; dt < 8; dt++)
      yrow[dt*16 + (lane & 15)] = f2bf(o[dt][r] * invl);
  }
}

// ---------------- temporal causal attention: KV-split flash, SWAPPED QK^T + defer-max ----------------
__global__ __launch_bounds__(256) void temporal_attn_split_kernel(
    const ushort* __restrict__ qkv, ushort* __restrict__ Op, float* __restrict__ ml)
{
  __shared__ __attribute__((aligned(16))) char Ks[64*128];
  __shared__ __attribute__((aligned(16))) char Vt[64*128];
  __shared__ __attribute__((aligned(16))) char Ps[4*16*128];
  int id = blockIdx.x;
  int bh = id & 15;
  int rest = id >> 4;
  int qt = 31 - (rest >> 1);
  int half = rest & 1;
  int b = bh >> 3, h = bh & 7;
  int tid = threadIdx.x, lane = tid & 63, w = tid >> 6;
  int g = lane >> 4, q = lane & 15;
  const ushort* base = qkv + (size_t)(b*2048)*1536 + h*64;

  int nk = qt + 1;
  int ktm = (nk + 1) >> 1;
  int kt0 = half ? ktm : 0;
  int kt1 = half ? nk : ktm;

  int qrow = qt*64 + w*16 + q;
  bf16x8 qb[2];
  #pragma unroll
  for (int kc = 0; kc < 2; kc++)
    qb[kc] = *(const bf16x8*)(base + (size_t)qrow*1536 + 512 + kc*32 + g*8);

  f32x4 zero4 = {0.f,0.f,0.f,0.f};
  f32x4 o[4];
  #pragma unroll
  for (int dt = 0; dt < 4; dt++) o[dt] = zero4;
  float m_old = -1e30f, l_sum = 0.f;

  int kcolsrc = ((lane & 7) ^ (lane >> 3)) * 16;
  int vj  = (tid & 31) * 2;
  int vd0 = (tid >> 5) * 8;
  int vcb = 4 * (tid & 31);
  char* myP = Ps + w*2048;
  int pswz = (q & 7) << 4;

  for (int kt = kt0; kt < kt1; kt++){
    __syncthreads();
    #pragma unroll
    for (int i = 0; i < 2; i++){
      int row = w*16 + i*8 + (lane >> 3);
      gload_lds16((const char*)(base + (size_t)(kt*64 + row)*1536) + kcolsrc,
                  Ks + (w*16 + i*8)*128);
    }
    {
      const ushort* v0p = base + (size_t)(kt*64 + vj)*1536 + 1024 + vd0;
      const ushort* v1p = v0p + 1536;
      uint4 a0 = *(const uint4*)v0p;
      uint4 b0 = *(const uint4*)v1p;
      uint av[4] = {a0.x, a0.y, a0.z, a0.w};
      uint bv[4] = {b0.x, b0.y, b0.z, b0.w};
      #pragma unroll
      for (int e = 0; e < 4; e++){
        int dl = vd0 + e*2, dh = dl + 1;
        uint vlo = (av[e] & 0xffffu) | ((bv[e] & 0xffffu) << 16);
        uint vhi = (av[e] >> 16) | (bv[e] & 0xffff0000u);
        *(uint*)(Vt + dl*128 + (vcb ^ ((dl & 7) << 4))) = vlo;
        *(uint*)(Vt + dh*128 + (vcb ^ ((dh & 7) << 4))) = vhi;
      }
    }
    __syncthreads();

    f32x4 accS[4];
    __builtin_amdgcn_s_setprio(1);
    #pragma unroll
    for (int jt = 0; jt < 4; jt++){
      accS[jt] = zero4;
      #pragma unroll
      for (int kc = 0; kc < 2; kc++){
        int krow = jt*16 + q;
        bf16x8 kb = *(const bf16x8*)(Ks + krow*128 + ((kc*64 + g*16) ^ ((krow & 7) << 4)));
        accS[jt] = __builtin_amdgcn_mfma_f32_16x16x32_bf16(kb, qb[kc], accS[jt], 0, 0, 0);
      }
    }
    __builtin_amdgcn_s_setprio(0);
    if (kt == qt){
      int gi = qt*64 + w*16 + q;
      #pragma unroll
      for (int jt = 0; jt < 4; jt++)
        #pragma unroll
        for (int r = 0; r < 4; r++){
          int gj = kt*64 + jt*16 + g*4 + r;
          if (gj > gi) accS[jt][r] = -1e30f;
        }
    }
    float mloc = fmaxf(fmaxf(accS[0][0], accS[0][1]), fmaxf(accS[0][2], accS[0][3]));
    #pragma unroll
    for (int jt = 1; jt < 4; jt++){
      float t2 = fmaxf(fmaxf(accS[jt][0], accS[jt][1]), fmaxf(accS[jt][2], accS[jt][3]));
      mloc = fmaxf(mloc, t2);
    }
    mloc *= 0.125f;
    mloc = fmaxf(mloc, __shfl_xor(mloc, 16, 64));
    mloc = fmaxf(mloc, __shfl_xor(mloc, 32, 64));
    if (!__all(mloc <= m_old + 8.f)){
      float mnew = fmaxf(m_old, mloc);
      float corr = __expf(m_old - mnew);
      l_sum *= corr;
      #pragma unroll
      for (int dt = 0; dt < 4; dt++) o[dt] *= corr;
      m_old = mnew;
    }
    float ps = 0.f;
    #pragma unroll
    for (int jt = 0; jt < 4; jt++){
      ushort pb0 = f2bf(__expf(accS[jt][0]*0.125f - m_old));
      ushort pb1 = f2bf(__expf(accS[jt][1]*0.125f - m_old));
      ushort pb2 = f2bf(__expf(accS[jt][2]*0.125f - m_old));
      ushort pb3 = f2bf(__expf(accS[jt][3]*0.125f - m_old));
      ps += bf2f(pb0) + bf2f(pb1) + bf2f(pb2) + bf2f(pb3);
      uint2 wv;
      wv.x = (uint)pb0 | ((uint)pb1 << 16);
      wv.y = (uint)pb2 | ((uint)pb3 << 16);
      *(uint2*)(myP + q*128 + ((jt*32 + g*8) ^ pswz)) = wv;
    }
    l_sum += ps;

    bf16x8 pfr[2];
    #pragma unroll
    for (int kc2 = 0; kc2 < 2; kc2++)
      pfr[kc2] = *(const bf16x8*)(myP + q*128 + ((kc2*64 + g*16) ^ pswz));
    __builtin_amdgcn_s_setprio(1);
    #pragma unroll
    for (int dt = 0; dt < 4; dt++){
      #pragma unroll
      for (int kc2 = 0; kc2 < 2; kc2++){
        int vrow = dt*16 + q;
        bf16x8 vb = *(const bf16x8*)(Vt + vrow*128 + ((kc2*64 + g*16) ^ ((vrow & 7) << 4)));
        o[dt] = __builtin_amdgcn_mfma_f32_16x16x32_bf16(vb, pfr[kc2], o[dt], 0, 0, 0);
      }
    }
    __builtin_amdgcn_s_setprio(0);
  }
  l_sum += __shfl_xor(l_sum, 16, 64);
  l_sum += __shfl_xor(l_sum, 32, 64);
  size_t tokbase = (size_t)half*4096 + (size_t)b*2048;
  int token = qt*64 + w*16 + q;
  ushort* yrow = Op + (tokbase + token)*512 + h*64;
  #pragma unroll
  for (int dt = 0; dt < 4; dt++){
    ushort4 o4;
    o4.x = f2bf(o[dt][0]); o4.y = f2bf(o[dt][1]);
    o4.z = f2bf(o[dt][2]); o4.w = f2bf(o[dt][3]);
    *(ushort4*)(yrow + dt*16 + g*4) = o4;
  }
  if (g == 0){
    float* mlp = ml + ((tokbase + token)*8 + h)*2;
    mlp[0] = m_old;
    mlp[1] = l_sum;
  }
}

// ---------------- merge the two KV-split halves -> bf16 attn out ----------------
__global__ __launch_bounds__(256) void attn_merge_kernel(
    const ushort* __restrict__ Op, const float* __restrict__ ml, ushort* __restrict__ Ef)
{
  int tok = blockIdx.x*4 + (threadIdx.x >> 6);
  int l6 = threadIdx.x & 63;
  int h = l6 >> 3, d0 = (l6 & 7)*8;
  int e = h*64 + d0;
  const float* m1p = ml + ((size_t)tok*8 + h)*2;
  const float* m2p = ml + (((size_t)4096 + tok)*8 + h)*2;
  float m1 = m1p[0], l1 = m1p[1];
  float m2 = m2p[0], l2 = m2p[1];
  float mm = fmaxf(m1, m2);
  float w1 = __expf(m1 - mm), w2 = __expf(m2 - mm);
  float inv = 1.f / (w1*l1 + w2*l2);
  uint4 a = *(const uint4*)(Op + (size_t)tok*512 + e);
  uint4 bq = *(const uint4*)(Op + ((size_t)4096 + tok)*512 + e);
  uint av[4] = {a.x, a.y, a.z, a.w};
  uint bv[4] = {bq.x, bq.y, bq.z, bq.w};
  uint ov[4];
  #pragma unroll
  for (int p = 0; p < 4; p++){
    float x0 = (w1*bf2f((ushort)(av[p] & 0xffff)) + w2*bf2f((ushort)(bv[p] & 0xffff))) * inv;
    float x1 = (w1*bf2f((ushort)(av[p] >> 16))    + w2*bf2f((ushort)(bv[p] >> 16)))    * inv;
    ov[p] = (uint)f2bf(x0) | ((uint)f2bf(x1) << 16);
  }
  uint4 o; o.x = ov[0]; o.y = ov[1]; o.z = ov[2]; o.w = ov[3];
  *(uint4*)(Ef + (size_t)tok*512 + e) = o;
}

// ---------------- tf = mean over N of lnf(hid) (bf16 in, f32 out) ----------------
__global__ __launch_bounds__(256) void reduce_tf_kernel(const ushort* __restrict__ hid, float* __restrict__ tf){
  int bt = blockIdx.x, tid = threadIdx.x;
  for (int d = tid; d < 512; d += 256){
    float s = 0.f;
    for (int n = 0; n < 64; n++) s += bf2f(hid[((size_t)bt*64 + n)*512 + d]);
    tf[(size_t)bt*512 + d] = s * (1.f/64.f);
  }
}

// ---------------- heads ----------------
__global__ __launch_bounds__(256) void head_kernel(
    const float* __restrict__ tf,
    const float* __restrict__ th_w1, const float* __restrict__ th_b1,
    const float* __restrict__ th_w2, const float* __restrict__ th_b2,
    const float* __restrict__ sh_w1, const float* __restrict__ sh_b1,
    const float* __restrict__ sh_w2, const float* __restrict__ sh_b2,
    const float* __restrict__ pf_w1, const float* __restrict__ pf_b1,
    const float* __restrict__ pf_w2, const float* __restrict__ pf_b2,
    float* __restrict__ out)
{
  __shared__ float z[512];
  __shared__ float red[4];
  int bi = blockIdx.x, tid = threadIdx.x;
  const float *w1, *b1, *w2, *b2;
  float* dst;
  if (bi < 64){
    w1 = pf_w1; b1 = pf_b1; w2 = pf_w2; b2 = pf_b2; dst = out + 4 + bi;
    z[tid]       = tf[(size_t)bi*512 + tid];
    z[tid + 256] = tf[(size_t)bi*512 + tid + 256];
  } else if (bi < 66){
    int b = bi - 64;
    w1 = th_w1; b1 = th_b1; w2 = th_w2; b2 = th_b2; dst = out + b;
    z[tid]       = tf[(size_t)(b*32 + 31)*512 + tid];
    z[tid + 256] = tf[(size_t)(b*32 + 31)*512 + tid + 256];
  } else {
    int b = bi - 66;
    w1 = sh_w1; b1 = sh_b1; w2 = sh_w2; b2 = sh_b2; dst = out + 2 + b;
    float s0 = 0.f, s1 = 0.f;
    for (int t = 0; t < 32; t++){
      s0 += tf[(size_t)(b*32 + t)*512 + tid];
      s1 += tf[(size_t)(b*32 + t)*512 + tid + 256];
    }
    z[tid] = s0 * (1.f/32.f); z[tid + 256] = s1 * (1.f/32.f);
  }
  __syncthreads();
  float a = b1[tid];
  const float* wrow = w1 + (size_t)tid * 512;
  for (int k = 0; k < 512; k++) a = fmaf(wrow[k], z[k], a);
  a = (a > 0.f) ? a : 0.2f * a;
  float s = blockReduceSum(a * w2[tid], red);
  if (tid == 0) *dst = s + b2[0];
}

__global__ __launch_bounds__(64) void final_kernel(float* __restrict__ out){
  int b = threadIdx.x;
  if (b < 2){
    float s = 0.f;
    for (int t = 0; t < 32; t++) s += out[4 + b*32 + t];
    out[68 + b] = out[b] + out[2 + b] + s * (1.f/32.f);
  }
}

extern "C" void kernel_launch(void* const* d_in, const int* in_sizes, int n_in,
                              void* d_out, int out_size, void* d_ws, size_t ws_size,
                              hipStream_t stream)
{
  const float* x          = (const float*)d_in[0];
  const float* patch_w    = (const float*)d_in[1];
  const float* patch_b    = (const float*)d_in[2];
  const float* tok_ln_g   = (const float*)d_in[3];
  const float* tok_ln_b   = (const float*)d_in[4];
  const float* spatial_pos= (const float*)d_in[5];
  const float* temporal_pos=(const float*)d_in[6];
  const float* snorm_g    = (const float*)d_in[7];
  const float* snorm_b    = (const float*)d_in[8];
  const float* sa_in_w    = (const float*)d_in[9];
  const float* sa_in_b    = (const float*)d_in[10];
  const float* sa_out_w   = (const float*)d_in[11];
  const float* sa_out_b   = (const float*)d_in[12];
  const float* ln1_g      = (const float*)d_in[13];
  const float* ln1_b      = (const float*)d_in[14];
  const float* kqv_w      = (const float*)d_in[15];
  const float* kqv_b      = (const float*)d_in[16];
  const float* proj_w     = (const float*)d_in[17];
  const float* proj_b     = (const float*)d_in[18];
  const float* ln2_g      = (const float*)d_in[19];
  const float* ln2_b      = (const float*)d_in[20];
  const float* fc_w       = (const float*)d_in[21];
  const float* fc_b       = (const float*)d_in[22];
  const float* cproj_w    = (const float*)d_in[23];
  const float* cproj_b    = (const float*)d_in[24];
  const float* lnf_g      = (const float*)d_in[25];
  const float* lnf_b      = (const float*)d_in[26];
  const float* th_w1 = (const float*)d_in[27];
  const float* th_b1 = (const float*)d_in[28];
  const float* th_w2 = (const float*)d_in[29];
  const float* th_b2 = (const float*)d_in[30];
  const float* sh_w1 = (const float*)d_in[31];
  const float* sh_b1 = (const float*)d_in[32];
  const float* sh_w2 = (const float*)d_in[33];
  const float* sh_b2 = (const float*)d_in[34];
  const float* pf_w1 = (const float*)d_in[35];
  const float* pf_b1 = (const float*)d_in[36];
  const float* pf_w2 = (const float*)d_in[37];
  const float* pf_b2 = (const float*)d_in[38];

  float* out = (float*)d_out;
  // workspace layout (bytes)
  char* p = (char*)d_ws;
  float*  A  = (float*)p;      p += (size_t)MTOK*512*4;    // f32 hidden
  ushort* Ru = (ushort*)p;     p += (size_t)MTOK*2048*2;   // bf16 qkv/gelu; f32 patch-gemm out
  ushort* Bf = (ushort*)p;     p += (size_t)MTOK*512*2;    // ln out bf16
  ushort* Ef = (ushort*)p;     p += (size_t)MTOK*512*2;    // attn out bf16 (also im2col patches)
  float*  tfp = (float*)p;     p += (size_t)64*512*4;
  ushort* OpB = (ushort*)p;    p += (size_t)2*MTOK*512*2;  // kv-split partial O (2 halves)
  float*  mlB = (float*)p;     p += (size_t)2*MTOK*8*2*4;  // kv-split (m,l)
  ushort* Wslot = (ushort*)p;  p += (size_t)1048576*2;     // fallback weight slot
  ushort* Wall = (ushort*)p;   p += (size_t)W_TOTAL*2;     // upfront bf16 arena
  const size_t NEED_BIG = (size_t)(p - (char*)d_ws);
  float*  Yp = (float*)p;      p += (size_t)2*MTOK*512*4;  // cproj K-split f32 partials
  const size_t NEED_SPLIT = (size_t)(p - (char*)d_ws);
  float*  Pf = (float*)Ru;     // patch gemm f32 out 4096x512
  ushort* Pm = Ef;             // patches bf16 4096x192 (before Ef first written)

  const bool big   = (ws_size >= NEED_BIG);
  const bool ksplt = (ws_size >= NEED_SPLIT);

  if (big){
    cvt_all_kernel<<<10800, 256, 0, stream>>>(patch_w, sa_in_w, sa_out_w, kqv_w,
                                              proj_w, fc_w, cproj_w, Wall);
  }
  auto W = [&](const float* src, size_t arena_off, size_t nelem) -> const ushort* {
    if (big) return Wall + arena_off;
    cvt_w_kernel<<<(int)(nelem/2048), 256, 0, stream>>>(src, Wslot, (int)nelem);
    return Wslot;
  };

  // patch embed: im2col -> MFMA GEMM -> LN+pos
  im2col_kernel<<<384, 256, 0, stream>>>(x, Pm);
  gemm2_kernel<64,64,false,false><<<dim3(8, 64), 256, 0, stream>>>(
      Pm, W(patch_w, OFF_PATCH, 512*192), patch_b, nullptr, Pf, MTOK, 512, 192, 192, 0, 0);
  ln_pos_kernel<<<1024, 256, 0, stream>>>(Pf, A, tok_ln_g, tok_ln_b, spatial_pos, temporal_pos);

  // spatial layers
  for (int i = 0; i < 3; i++){
    ln_bf16_kernel<<<1024, 256, 0, stream>>>(A, Bf, snorm_g, snorm_b);
    gemm2_kernel<64,64,false,true><<<dim3(24, 64), 256, 0, stream>>>(
        Bf, W(sa_in_w + (size_t)i*1536*512, OFF_SAIN + (size_t)i*786432, 1536*512),
        sa_in_b + (size_t)i*1536, nullptr, Ru, MTOK, 1536, 512, 512, 0, 0);
    spatial_attn_mfma_kernel<<<dim3(64, 4), 256, 0, stream>>>(Ru, Ef);
    gemm2_kernel<64,64,false,false><<<dim3(8, 64), 256, 0, stream>>>(
        Ef, W(sa_out_w + (size_t)i*512*512, OFF_SAOUT + (size_t)i*262144, 512*512),
        sa_out_b + (size_t)i*512, A, A, MTOK, 512, 512, 512, 0, 0);
  }
  // temporal layers (kv-split flash + merge)
  for (int i = 0; i < 6; i++){
    ln_bf16_kernel<<<1024, 256, 0, stream>>>(A, Bf, ln1_g + (size_t)i*512, ln1_b + (size_t)i*512);
    gemm2_kernel<64,64,false,true><<<dim3(24, 64), 256, 0, stream>>>(
        Bf, W(kqv_w + (size_t)i*1536*512, OFF_KQV + (size_t)i*786432, 1536*512),
        kqv_b + (size_t)i*1536, nullptr, Ru, MTOK, 1536, 512, 512, 0, 0);
    temporal_attn_split_kernel<<<1024, 256, 0, stream>>>(Ru, OpB, mlB);
    attn_merge_kernel<<<1024, 256, 0, stream>>>(OpB, mlB, Ef);
    gemm2_kernel<64,64,false,false><<<dim3(8, 64), 256, 0, stream>>>(
        Ef, W(proj_w + (size_t)i*512*512, OFF_PROJ + (size_t)i*262144, 512*512),
        proj_b + (size_t)i*512, A, A, MTOK, 512, 512, 512, 0, 0);
    ln_bf16_kernel<<<1024, 256, 0, stream>>>(A, Bf, ln2_g + (size_t)i*512, ln2_b + (size_t)i*512);
    gemm2_kernel<64,64,true,true><<<dim3(32, 64), 256, 0, stream>>>(
        Bf, W(fc_w + (size_t)i*2048*512, OFF_FC + (size_t)i*1048576, 2048*512),
        fc_b + (size_t)i*2048, nullptr, Ru, MTOK, 2048, 512, 512, 0, 0);
    const ushort* cw = W(cproj_w + (size_t)i*512*2048, OFF_CPROJ + (size_t)i*1048576, 512*2048);
    if (ksplt){
      gemm2_kernel<64,64,false,false><<<dim3(8, 64, 2), 256, 0, stream>>>(
          Ru, cw, nullptr, nullptr, Yp, MTOK, 512, 1024, 2048, 1024, (size_t)MTOK*512*4);
      cproj_merge_kernel<<<2048, 256, 0, stream>>>(Yp, cproj_b + (size_t)i*512, A);
    } else {
      gemm2_kernel<64,64,false,false><<<dim3(8, 64), 256, 0, stream>>>(
          Ru, cw, cproj_b + (size_t)i*512, A, A, MTOK, 512, 2048, 2048, 0, 0);
    }
  }
  // final LN + heads
  ln_bf16_kernel<<<1024, 256, 0, stream>>>(A, Bf, lnf_g, lnf_b);
  reduce_tf_kernel<<<64, 256, 0, stream>>>(Bf, tfp);
  head_kernel<<<68, 256, 0, stream>>>(tfp, th_w1, th_b1, th_w2, th_b2,
                                      sh_w1, sh_b1, sh_w2, sh_b2,
                                      pf_w1, pf_b1, pf_w2, pf_b2, out);
  final_kernel<<<1, 64, 0, stream>>>(out);
}

// Round 15
// 802.980 us; speedup vs baseline: 1.0625x; 1.0625x over previous
//
#include <hip/hip_runtime.h>
#include <hip/hip_bf16.h>
#include <math.h>

// Sizes: B=2 T=32 C=3 H=W=64 P=8 -> N=64, D=512, L=2048, M=B*T*N=4096
#define MTOK 4096

typedef __bf16 bf16x8 __attribute__((ext_vector_type(8)));
typedef float f32x4 __attribute__((ext_vector_type(4)));

__device__ __forceinline__ ushort f2bf(float f){
  __hip_bfloat16 h = __float2bfloat16(f);
  return *reinterpret_cast<ushort*>(&h);
}
__device__ __forceinline__ float bf2f(ushort u){
  return __uint_as_float(((uint)u) << 16);
}
__device__ __forceinline__ void gload_lds16(const void* g, void* l){
  __builtin_amdgcn_global_load_lds((__attribute__((address_space(1))) void*)(void*)g,
                                   (__attribute__((address_space(3))) void*)l, 16, 0, 0);
}

__device__ __forceinline__ float blockReduceSum(float v, float* red){
  #pragma unroll
  for (int off = 32; off; off >>= 1) v += __shfl_down(v, off, 64);
  int lane = threadIdx.x & 63, wid = threadIdx.x >> 6;
  __syncthreads();
  if (lane == 0) red[wid] = v;
  __syncthreads();
  float r = 0.f;
  int nw = blockDim.x >> 6;
  for (int i = 0; i < nw; i++) r += red[i];
  return r;
}
__device__ __forceinline__ float rowMax16(float v){
  #pragma unroll
  for (int m = 8; m; m >>= 1) v = fmaxf(v, __shfl_xor(v, m, 64));
  return v;
}
__device__ __forceinline__ float rowSum16(float v){
  #pragma unroll
  for (int m = 8; m; m >>= 1) v += __shfl_xor(v, m, 64);
  return v;
}

// ---------------- weight f32 -> bf16 (per-matrix fallback) ----------------
__global__ __launch_bounds__(256) void cvt_w_kernel(
    const float* __restrict__ src, ushort* __restrict__ dst, int n)
{
  int i = (blockIdx.x * 256 + threadIdx.x) * 8;
  float4 a = *(const float4*)(src + i);
  float4 b = *(const float4*)(src + i + 4);
  uint4 o;
  o.x = (uint)f2bf(a.x) | ((uint)f2bf(a.y) << 16);
  o.y = (uint)f2bf(a.z) | ((uint)f2bf(a.w) << 16);
  o.z = (uint)f2bf(b.x) | ((uint)f2bf(b.y) << 16);
  o.w = (uint)f2bf(b.z) | ((uint)f2bf(b.w) << 16);
  *(uint4*)(dst + i) = o;
}

// ---------------- all weights -> bf16 arena (one dispatch) ----------------
#define OFF_PATCH 0u
#define OFF_SAIN  98304u
#define OFF_SAOUT 2457600u
#define OFF_KQV   3244032u
#define OFF_PROJ  7962624u
#define OFF_FC    9535488u
#define OFF_CPROJ 15826944u
#define W_TOTAL   22118400u
__global__ __launch_bounds__(256) void cvt_all_kernel(
    const float* __restrict__ pw, const float* __restrict__ sain,
    const float* __restrict__ saout, const float* __restrict__ kqv,
    const float* __restrict__ proj, const float* __restrict__ fc,
    const float* __restrict__ cproj, ushort* __restrict__ dst)
{
  int blk = blockIdx.x;
  const float* src; size_t off;
  if      (blk <    48){ src = pw;    off = OFF_PATCH; }
  else if (blk <  1200){ src = sain;  off = OFF_SAIN;  blk -= 48;   }
  else if (blk <  1584){ src = saout; off = OFF_SAOUT; blk -= 1200; }
  else if (blk <  3888){ src = kqv;   off = OFF_KQV;   blk -= 1584; }
  else if (blk <  4656){ src = proj;  off = OFF_PROJ;  blk -= 3888; }
  else if (blk <  7728){ src = fc;    off = OFF_FC;    blk -= 4656; }
  else                 { src = cproj; off = OFF_CPROJ; blk -= 7728; }
  size_t si = (size_t)blk*2048 + threadIdx.x*8;
  float4 a = *(const float4*)(src + si);
  float4 b = *(const float4*)(src + si + 4);
  uint4 o;
  o.x = (uint)f2bf(a.x) | ((uint)f2bf(a.y) << 16);
  o.y = (uint)f2bf(a.z) | ((uint)f2bf(a.w) << 16);
  o.z = (uint)f2bf(b.x) | ((uint)f2bf(b.y) << 16);
  o.w = (uint)f2bf(b.z) | ((uint)f2bf(b.w) << 16);
  *(uint4*)(dst + off + si) = o;
}

// ---------------- im2col: x -> patches [4096][192] bf16 ----------------
__global__ __launch_bounds__(256) void im2col_kernel(
    const float* __restrict__ x, ushort* __restrict__ Pm)
{
  int idx = blockIdx.x*256 + threadIdx.x;   // 0..98303
  int m = idx / 24, e8 = idx % 24;
  int b = m >> 11, t = (m >> 6) & 31, n = m & 63;
  int hn = n >> 3, wn = n & 7;
  int c = e8 >> 3, ph = e8 & 7;
  const float* src = x + (((size_t)(b*32 + t)*3 + c)*64 + hn*8 + ph)*64 + wn*8;
  float4 a = *(const float4*)src;
  float4 bq = *(const float4*)(src + 4);
  uint4 o;
  o.x = (uint)f2bf(a.x) | ((uint)f2bf(a.y) << 16);
  o.y = (uint)f2bf(a.z) | ((uint)f2bf(a.w) << 16);
  o.z = (uint)f2bf(bq.x) | ((uint)f2bf(bq.y) << 16);
  o.w = (uint)f2bf(bq.z) | ((uint)f2bf(bq.w) << 16);
  *(uint4*)(Pm + (size_t)m*192 + e8*8) = o;
}

// ---------------- tok LN + pos (wave per row, 4 rows/block) ----------------
__global__ __launch_bounds__(256) void ln_pos_kernel(
    const float* __restrict__ in, float* __restrict__ out,
    const float* __restrict__ g, const float* __restrict__ b,
    const float* __restrict__ spos, const float* __restrict__ tpos)
{
  int r = blockIdx.x*4 + (threadIdx.x >> 6);
  int lane = threadIdx.x & 63;
  int n = r & 63, t = (r >> 6) & 31;
  const float* row = in + (size_t)r*512 + lane*8;
  float4 v0 = *(const float4*)row;
  float4 v1 = *(const float4*)(row + 4);
  float s = v0.x+v0.y+v0.z+v0.w+v1.x+v1.y+v1.z+v1.w;
  float q = v0.x*v0.x+v0.y*v0.y+v0.z*v0.z+v0.w*v0.w+v1.x*v1.x+v1.y*v1.y+v1.z*v1.z+v1.w*v1.w;
  #pragma unroll
  for (int m = 1; m < 64; m <<= 1){ s += __shfl_xor(s, m, 64); q += __shfl_xor(q, m, 64); }
  float mu = s*(1.f/512.f);
  float inv = rsqrtf(q*(1.f/512.f) - mu*mu + 1e-5f);
  const float* gp = g + lane*8;
  const float* bp = b + lane*8;
  const float* sp = spos + n*512 + lane*8;
  const float* tp = tpos + t*512 + lane*8;
  float* op = out + (size_t)r*512 + lane*8;
  #pragma unroll
  for (int e = 0; e < 2; e++){
    float4 vv = e ? v1 : v0;
    float4 gg = *(const float4*)(gp + e*4);
    float4 bb = *(const float4*)(bp + e*4);
    float4 ss = *(const float4*)(sp + e*4);
    float4 tt = *(const float4*)(tp + e*4);
    float4 oo;
    oo.x = (vv.x-mu)*inv*gg.x + bb.x + ss.x + tt.x;
    oo.y = (vv.y-mu)*inv*gg.y + bb.y + ss.y + tt.y;
    oo.z = (vv.z-mu)*inv*gg.z + bb.z + ss.z + tt.z;
    oo.w = (vv.w-mu)*inv*gg.w + bb.w + ss.w + tt.w;
    *(float4*)(op + e*4) = oo;
  }
}

// ---------------- LayerNorm (D=512) fp32 in -> bf16 out (wave per row) ----------------
__global__ __launch_bounds__(256) void ln_bf16_kernel(
    const float* __restrict__ in, ushort* __restrict__ out,
    const float* __restrict__ g, const float* __restrict__ b)
{
  int r = blockIdx.x*4 + (threadIdx.x >> 6);
  int lane = threadIdx.x & 63;
  const float* row = in + (size_t)r*512 + lane*8;
  float4 v0 = *(const float4*)row;
  float4 v1 = *(const float4*)(row + 4);
  float s = v0.x+v0.y+v0.z+v0.w+v1.x+v1.y+v1.z+v1.w;
  float q = v0.x*v0.x+v0.y*v0.y+v0.z*v0.z+v0.w*v0.w+v1.x*v1.x+v1.y*v1.y+v1.z*v1.z+v1.w*v1.w;
  #pragma unroll
  for (int m = 1; m < 64; m <<= 1){ s += __shfl_xor(s, m, 64); q += __shfl_xor(q, m, 64); }
  float mu = s*(1.f/512.f);
  float inv = rsqrtf(q*(1.f/512.f) - mu*mu + 1e-5f);
  float4 g0 = *(const float4*)(g + lane*8);
  float4 g1 = *(const float4*)(g + lane*8 + 4);
  float4 b0 = *(const float4*)(b + lane*8);
  float4 b1 = *(const float4*)(b + lane*8 + 4);
  uint4 o;
  o.x = (uint)f2bf((v0.x-mu)*inv*g0.x + b0.x) | ((uint)f2bf((v0.y-mu)*inv*g0.y + b0.y) << 16);
  o.y = (uint)f2bf((v0.z-mu)*inv*g0.z + b0.z) | ((uint)f2bf((v0.w-mu)*inv*g0.w + b0.w) << 16);
  o.z = (uint)f2bf((v1.x-mu)*inv*g1.x + b1.x) | ((uint)f2bf((v1.y-mu)*inv*g1.y + b1.y) << 16);
  o.w = (uint)f2bf((v1.z-mu)*inv*g1.z + b1.z) | ((uint)f2bf((v1.w-mu)*inv*g1.w + b1.w) << 16);
  *(uint4*)(out + (size_t)r*512 + lane*8) = o;
}

// ---------------- MFMA GEMM v2 ----------------
// WSB=false: both operands double-buffered (2*(BM+BN)*128 LDS), 1 barrier/step.
// WSB=true : X double-buffered, W single-buffered ((2*BM+BN)*128 LDS), 2 barriers/step.
template<int BM, int BN, bool GELU, bool BF16OUT, bool WSB>
__global__ __launch_bounds__(256) void gemm2_kernel(
    const ushort* __restrict__ X, const ushort* __restrict__ Wb,
    const float* __restrict__ bias, const float* __restrict__ res,
    void* __restrict__ Yv, int M, int Nn, int K)
{
  constexpr int WROWS = (BN == 128) ? 2 : 4;
  constexpr int WM = BM / WROWS;
  constexpr int FM = WM / 16;
  constexpr int FN = 4;
  constexpr int SMEM = WSB ? (2*BM+BN)*128 : 2*(BM+BN)*128;
  __shared__ __attribute__((aligned(16))) char smem[SMEM];
  int tid = threadIdx.x, lane = tid & 63, wv = tid >> 6;
  int bm = blockIdx.y * BM, bn = blockIdx.x * BN;
  int wm, wn;
  if (BN == 128){ wm = (wv >> 1) * WM; wn = (wv & 1) * 64; }
  else          { wm = wv * WM;        wn = 0; }

  f32x4 acc[FM][FN];
  #pragma unroll
  for (int i = 0; i < FM; i++)
    #pragma unroll
    for (int j = 0; j < FN; j++){ f32x4 z = {0.f,0.f,0.f,0.f}; acc[i][j] = z; }

  int rowoff = wv*8 + (lane >> 3);
  int colsrc = ((lane & 7) ^ (lane >> 3)) * 16;

  auto stageX = [&](char* Xd, int k0){
    #pragma unroll
    for (int i = 0; i < BM/32; i++){
      int row = i*32 + rowoff;
      gload_lds16((const char*)(X + (size_t)(bm + row)*K + k0) + colsrc,
                  Xd + (i*32 + wv*8)*128);
    }
  };
  auto stageW = [&](char* Wd, int k0){
    #pragma unroll
    for (int i = 0; i < BN/32; i++){
      int row = i*32 + rowoff;
      gload_lds16((const char*)(Wb + (size_t)(bn + row)*K + k0) + colsrc,
                  Wd + (i*32 + wv*8)*128);
    }
  };
  auto compute = [&](const char* Xc, const char* Wc){
    #pragma unroll
    for (int kc = 0; kc < 2; kc++){
      bf16x8 a[FM], b[FN];
      #pragma unroll
      for (int f = 0; f < FM; f++){
        int ra = wm + f*16 + (lane & 15);
        a[f] = *(const bf16x8*)(Xc + ra*128 + ((kc*64 + (lane>>4)*16) ^ ((ra & 7) << 4)));
      }
      #pragma unroll
      for (int f = 0; f < FN; f++){
        int rb = wn + f*16 + (lane & 15);
        b[f] = *(const bf16x8*)(Wc + rb*128 + ((kc*64 + (lane>>4)*16) ^ ((rb & 7) << 4)));
      }
      #pragma unroll
      for (int i = 0; i < FM; i++)
        #pragma unroll
        for (int j = 0; j < FN; j++)
          acc[i][j] = __builtin_amdgcn_mfma_f32_16x16x32_bf16(a[i], b[j], acc[i][j], 0, 0, 0);
    }
  };

  int nt = K >> 6;
  if constexpr (WSB){
    char* Xs0 = smem;
    char* Xs1 = smem + BM*128;
    char* WsS = smem + 2*BM*128;
    stageX(Xs0, 0);
    stageW(WsS, 0);
    __syncthreads();
    for (int t = 0; t < nt; t++){
      char* Xc = (t & 1) ? Xs1 : Xs0;
      if (t + 1 < nt) stageX((t & 1) ? Xs0 : Xs1, (t+1)*64);
      compute(Xc, WsS);
      __syncthreads();                  // X(t+1) landed; W reads done
      if (t + 1 < nt) stageW(WsS, (t+1)*64);
      __syncthreads();                  // W(t+1) drained
    }
  } else {
    char* Xs0 = smem;
    char* Ws0 = smem + BM*128;
    char* Xs1 = smem + (BM+BN)*128;
    char* Ws1 = Xs1 + BM*128;
    stageX(Xs0, 0);
    stageW(Ws0, 0);
    __syncthreads();
    for (int t = 0; t < nt; t++){
      char* Xc = (t & 1) ? Xs1 : Xs0;
      char* Wc = (t & 1) ? Ws1 : Ws0;
      if (t + 1 < nt){
        stageX((t & 1) ? Xs0 : Xs1, (t+1)*64);
        stageW((t & 1) ? Ws0 : Ws1, (t+1)*64);
      }
      compute(Xc, Wc);
      __syncthreads();
    }
  }

  int col0 = lane & 15;
  float bv[FN];
  #pragma unroll
  for (int fn = 0; fn < FN; fn++) bv[fn] = bias[bn + wn + fn*16 + col0];
  #pragma unroll
  for (int fm = 0; fm < FM; fm++){
    #pragma unroll
    for (int r = 0; r < 4; r++){
      int m = bm + wm + fm*16 + (lane >> 4)*4 + r;
      #pragma unroll
      for (int fn = 0; fn < FN; fn++){
        int n = bn + wn + fn*16 + col0;
        float v = acc[fm][fn][r] + bv[fn];
        if (res) v += res[(size_t)m*Nn + n];
        if (GELU) v = 0.5f * v * (1.f + erff(v * 0.70710678118654752440f));
        if (BF16OUT) ((ushort*)Yv)[(size_t)m*Nn + n] = f2bf(v);
        else         ((float*) Yv)[(size_t)m*Nn + n] = v;
      }
    }
  }
}

// ---------------- spatial attention, bf16 MFMA ----------------
__global__ __launch_bounds__(256) void spatial_attn_mfma_kernel(
    const ushort* __restrict__ qkv, ushort* __restrict__ y)
{
  __shared__ __attribute__((aligned(16))) char Ks[64*256];
  __shared__ __attribute__((aligned(16))) char Vt[128*128];
  __shared__ __attribute__((aligned(16))) char Ps[64*128];
  int bt = blockIdx.x, h = blockIdx.y;
  int tid = threadIdx.x, lane = tid & 63, w = tid >> 6;
  const ushort* base = qkv + (size_t)bt*64*1536 + (size_t)h*128;
  const float scale = 0.08838834764831845f;

  int qrow = w*16 + (lane & 15);
  bf16x8 qa[4];
  #pragma unroll
  for (int kc = 0; kc < 4; kc++)
    qa[kc] = *(const bf16x8*)(base + (size_t)qrow*1536 + kc*32 + (lane>>4)*8);

  #pragma unroll
  for (int i = 0; i < 4; i++){
    int row = w*16 + i*4 + (lane >> 4);
    const char* src = (const char*)(base + (size_t)row*1536 + 512) + (((lane & 15) ^ (row & 15)) * 16);
    char* dst = Ks + (w*16 + i*4)*256;
    gload_lds16(src, dst);
  }
  {
    int vj = (tid & 31) * 2;
    int d0 = (tid >> 5) * 16;
    const ushort* v0p = base + (size_t)vj*1536 + 1024 + d0;
    const ushort* v1p = v0p + 1536;
    uint4 a0 = *(const uint4*)(v0p);
    uint4 a1 = *(const uint4*)(v0p + 8);
    uint4 b0 = *(const uint4*)(v1p);
    uint4 b1 = *(const uint4*)(v1p + 8);
    uint av[8] = {a0.x, a0.y, a0.z, a0.w, a1.x, a1.y, a1.z, a1.w};
    uint bv[8] = {b0.x, b0.y, b0.z, b0.w, b1.x, b1.y, b1.z, b1.w};
    int cb = 4 * (tid & 31);
    #pragma unroll
    for (int e = 0; e < 8; e++){
      int dl = d0 + e*2, dh = dl + 1;
      uint vlo = (av[e] & 0xffffu) | ((bv[e] & 0xffffu) << 16);
      uint vhi = (av[e] >> 16) | (bv[e] & 0xffff0000u);
      *(uint*)(Vt + dl*128 + (cb ^ ((dl & 7) << 4))) = vlo;
      *(uint*)(Vt + dh*128 + (cb ^ ((dh & 7) << 4))) = vhi;
    }
  }
  __syncthreads();

  f32x4 zero4 = {0.f,0.f,0.f,0.f};
  f32x4 accS[4];
  __builtin_amdgcn_s_setprio(1);
  #pragma unroll
  for (int jt = 0; jt < 4; jt++){
    accS[jt] = zero4;
    #pragma unroll
    for (int kc = 0; kc < 4; kc++){
      int krow = jt*16 + (lane & 15);
      bf16x8 kb = *(const bf16x8*)(Ks + krow*256 + ((kc*64 + (lane>>4)*16) ^ ((krow & 15) << 4)));
      accS[jt] = __builtin_amdgcn_mfma_f32_16x16x32_bf16(qa[kc], kb, accS[jt], 0, 0, 0);
    }
  }
  __builtin_amdgcn_s_setprio(0);
  float l_sum[4];
  #pragma unroll
  for (int r = 0; r < 4; r++){
    float mx = fmaxf(fmaxf(accS[0][r], accS[1][r]), fmaxf(accS[2][r], accS[3][r]));
    mx = rowMax16(mx);
    int prow = w*16 + (lane>>4)*4 + r;
    int swz = (prow & 7) << 4;
    char* pbase = Ps + prow*128;
    float ps = 0.f;
    #pragma unroll
    for (int jt = 0; jt < 4; jt++){
      float p = __expf((accS[jt][r] - mx) * scale);
      ushort pb = f2bf(p);
      *(ushort*)(pbase + ((2*(jt*16 + (lane & 15))) ^ swz)) = pb;
      ps += bf2f(pb);
    }
    l_sum[r] = rowSum16(ps);
  }
  bf16x8 pa[2];
  #pragma unroll
  for (int kc2 = 0; kc2 < 2; kc2++){
    int prow = w*16 + (lane & 15);
    pa[kc2] = *(const bf16x8*)(Ps + prow*128 + ((kc2*64 + (lane>>4)*16) ^ ((prow & 7) << 4)));
  }
  f32x4 o[8];
  __builtin_amdgcn_s_setprio(1);
  #pragma unroll
  for (int dt = 0; dt < 8; dt++){
    o[dt] = zero4;
    #pragma unroll
    for (int kc2 = 0; kc2 < 2; kc2++){
      int vrow = dt*16 + (lane & 15);
      bf16x8 vb = *(const bf16x8*)(Vt + vrow*128 + ((kc2*64 + (lane>>4)*16) ^ ((vrow & 7) << 4)));
      o[dt] = __builtin_amdgcn_mfma_f32_16x16x32_bf16(pa[kc2], vb, o[dt], 0, 0, 0);
    }
  }
  __builtin_amdgcn_s_setprio(0);
  #pragma unroll
  for (int r = 0; r < 4; r++){
    float invl = 1.f / l_sum[r];
    int token = bt*64 + w*16 + (lane>>4)*4 + r;
    ushort* yrow = y + (size_t)token*512 + h*128;
    #pragma unroll
    for (int dt = 0; dt < 8; dt++)
      yrow[dt*16 + (lane & 15)] = f2bf(o[dt][r] * invl);
  }
}

// ---------------- temporal causal attention: KV-split flash, SWAPPED QK^T + defer-max ----------------
__global__ __launch_bounds__(256) void temporal_attn_split_kernel(
    const ushort* __restrict__ qkv, ushort* __restrict__ Op, float* __restrict__ ml)
{
  __shared__ __attribute__((aligned(16))) char Ks[64*128];
  __shared__ __attribute__((aligned(16))) char Vt[64*128];
  __shared__ __attribute__((aligned(16))) char Ps[4*16*128];
  int id = blockIdx.x;
  int bh = id & 15;
  int rest = id >> 4;
  int qt = 31 - (rest >> 1);
  int half = rest & 1;
  int b = bh >> 3, h = bh & 7;
  int tid = threadIdx.x, lane = tid & 63, w = tid >> 6;
  int g = lane >> 4, q = lane & 15;
  const ushort* base = qkv + (size_t)(b*2048)*1536 + h*64;

  int nk = qt + 1;
  int ktm = (nk + 1) >> 1;
  int kt0 = half ? ktm : 0;
  int kt1 = half ? nk : ktm;

  int qrow = qt*64 + w*16 + q;
  bf16x8 qb[2];
  #pragma unroll
  for (int kc = 0; kc < 2; kc++)
    qb[kc] = *(const bf16x8*)(base + (size_t)qrow*1536 + 512 + kc*32 + g*8);

  f32x4 zero4 = {0.f,0.f,0.f,0.f};
  f32x4 o[4];
  #pragma unroll
  for (int dt = 0; dt < 4; dt++) o[dt] = zero4;
  float m_old = -1e30f, l_sum = 0.f;

  int kcolsrc = ((lane & 7) ^ (lane >> 3)) * 16;
  int vj  = (tid & 31) * 2;
  int vd0 = (tid >> 5) * 8;
  int vcb = 4 * (tid & 31);
  char* myP = Ps + w*2048;
  int pswz = (q & 7) << 4;

  for (int kt = kt0; kt < kt1; kt++){
    __syncthreads();
    #pragma unroll
    for (int i = 0; i < 2; i++){
      int row = w*16 + i*8 + (lane >> 3);
      gload_lds16((const char*)(base + (size_t)(kt*64 + row)*1536) + kcolsrc,
                  Ks + (w*16 + i*8)*128);
    }
    {
      const ushort* v0p = base + (size_t)(kt*64 + vj)*1536 + 1024 + vd0;
      const ushort* v1p = v0p + 1536;
      uint4 a0 = *(const uint4*)v0p;
      uint4 b0 = *(const uint4*)v1p;
      uint av[4] = {a0.x, a0.y, a0.z, a0.w};
      uint bv[4] = {b0.x, b0.y, b0.z, b0.w};
      #pragma unroll
      for (int e = 0; e < 4; e++){
        int dl = vd0 + e*2, dh = dl + 1;
        uint vlo = (av[e] & 0xffffu) | ((bv[e] & 0xffffu) << 16);
        uint vhi = (av[e] >> 16) | (bv[e] & 0xffff0000u);
        *(uint*)(Vt + dl*128 + (vcb ^ ((dl & 7) << 4))) = vlo;
        *(uint*)(Vt + dh*128 + (vcb ^ ((dh & 7) << 4))) = vhi;
      }
    }
    __syncthreads();

    f32x4 accS[4];
    __builtin_amdgcn_s_setprio(1);
    #pragma unroll
    for (int jt = 0; jt < 4; jt++){
      accS[jt] = zero4;
      #pragma unroll
      for (int kc = 0; kc < 2; kc++){
        int krow = jt*16 + q;
        bf16x8 kb = *(const bf16x8*)(Ks + krow*128 + ((kc*64 + g*16) ^ ((krow & 7) << 4)));
        accS[jt] = __builtin_amdgcn_mfma_f32_16x16x32_bf16(kb, qb[kc], accS[jt], 0, 0, 0);
      }
    }
    __builtin_amdgcn_s_setprio(0);
    if (kt == qt){
      int gi = qt*64 + w*16 + q;
      #pragma unroll
      for (int jt = 0; jt < 4; jt++)
        #pragma unroll
        for (int r = 0; r < 4; r++){
          int gj = kt*64 + jt*16 + g*4 + r;
          if (gj > gi) accS[jt][r] = -1e30f;
        }
    }
    float mloc = fmaxf(fmaxf(accS[0][0], accS[0][1]), fmaxf(accS[0][2], accS[0][3]));
    #pragma unroll
    for (int jt = 1; jt < 4; jt++){
      float t2 = fmaxf(fmaxf(accS[jt][0], accS[jt][1]), fmaxf(accS[jt][2], accS[jt][3]));
      mloc = fmaxf(mloc, t2);
    }
    mloc *= 0.125f;
    mloc = fmaxf(mloc, __shfl_xor(mloc, 16, 64));
    mloc = fmaxf(mloc, __shfl_xor(mloc, 32, 64));
    if (!__all(mloc <= m_old + 8.f)){
      float mnew = fmaxf(m_old, mloc);
      float corr = __expf(m_old - mnew);
      l_sum *= corr;
      #pragma unroll
      for (int dt = 0; dt < 4; dt++) o[dt] *= corr;
      m_old = mnew;
    }
    float ps = 0.f;
    #pragma unroll
    for (int jt = 0; jt < 4; jt++){
      ushort pb0 = f2bf(__expf(accS[jt][0]*0.125f - m_old));
      ushort pb1 = f2bf(__expf(accS[jt][1]*0.125f - m_old));
      ushort pb2 = f2bf(__expf(accS[jt][2]*0.125f - m_old));
      ushort pb3 = f2bf(__expf(accS[jt][3]*0.125f - m_old));
      ps += bf2f(pb0) + bf2f(pb1) + bf2f(pb2) + bf2f(pb3);
      uint2 wv;
      wv.x = (uint)pb0 | ((uint)pb1 << 16);
      wv.y = (uint)pb2 | ((uint)pb3 << 16);
      *(uint2*)(myP + q*128 + ((jt*32 + g*8) ^ pswz)) = wv;
    }
    l_sum += ps;

    bf16x8 pfr[2];
    #pragma unroll
    for (int kc2 = 0; kc2 < 2; kc2++)
      pfr[kc2] = *(const bf16x8*)(myP + q*128 + ((kc2*64 + g*16) ^ pswz));
    __builtin_amdgcn_s_setprio(1);
    #pragma unroll
    for (int dt = 0; dt < 4; dt++){
      #pragma unroll
      for (int kc2 = 0; kc2 < 2; kc2++){
        int vrow = dt*16 + q;
        bf16x8 vb = *(const bf16x8*)(Vt + vrow*128 + ((kc2*64 + g*16) ^ ((vrow & 7) << 4)));
        o[dt] = __builtin_amdgcn_mfma_f32_16x16x32_bf16(vb, pfr[kc2], o[dt], 0, 0, 0);
      }
    }
    __builtin_amdgcn_s_setprio(0);
  }
  l_sum += __shfl_xor(l_sum, 16, 64);
  l_sum += __shfl_xor(l_sum, 32, 64);
  size_t tokbase = (size_t)half*4096 + (size_t)b*2048;
  int token = qt*64 + w*16 + q;
  ushort* yrow = Op + (tokbase + token)*512 + h*64;
  #pragma unroll
  for (int dt = 0; dt < 4; dt++){
    ushort4 o4;
    o4.x = f2bf(o[dt][0]); o4.y = f2bf(o[dt][1]);
    o4.z = f2bf(o[dt][2]); o4.w = f2bf(o[dt][3]);
    *(ushort4*)(yrow + dt*16 + g*4) = o4;
  }
  if (g == 0){
    float* mlp = ml + ((tokbase + token)*8 + h)*2;
    mlp[0] = m_old;
    mlp[1] = l_sum;
  }
}

// ---------------- merge the two KV-split halves -> bf16 attn out ----------------
__global__ __launch_bounds__(256) void attn_merge_kernel(
    const ushort* __restrict__ Op, const float* __restrict__ ml, ushort* __restrict__ Ef)
{
  int tok = blockIdx.x*4 + (threadIdx.x >> 6);
  int l6 = threadIdx.x & 63;
  int h = l6 >> 3, d0 = (l6 & 7)*8;
  int e = h*64 + d0;
  const float* m1p = ml + ((size_t)tok*8 + h)*2;
  const float* m2p = ml + (((size_t)4096 + tok)*8 + h)*2;
  float m1 = m1p[0], l1 = m1p[1];
  float m2 = m2p[0], l2 = m2p[1];
  float mm = fmaxf(m1, m2);
  float w1 = __expf(m1 - mm), w2 = __expf(m2 - mm);
  float inv = 1.f / (w1*l1 + w2*l2);
  uint4 a = *(const uint4*)(Op + (size_t)tok*512 + e);
  uint4 bq = *(const uint4*)(Op + ((size_t)4096 + tok)*512 + e);
  uint av[4] = {a.x, a.y, a.z, a.w};
  uint bv[4] = {bq.x, bq.y, bq.z, bq.w};
  uint ov[4];
  #pragma unroll
  for (int p = 0; p < 4; p++){
    float x0 = (w1*bf2f((ushort)(av[p] & 0xffff)) + w2*bf2f((ushort)(bv[p] & 0xffff))) * inv;
    float x1 = (w1*bf2f((ushort)(av[p] >> 16))    + w2*bf2f((ushort)(bv[p] >> 16)))    * inv;
    ov[p] = (uint)f2bf(x0) | ((uint)f2bf(x1) << 16);
  }
  uint4 o; o.x = ov[0]; o.y = ov[1]; o.z = ov[2]; o.w = ov[3];
  *(uint4*)(Ef + (size_t)tok*512 + e) = o;
}

// ---------------- tf = mean over N of lnf(hid) (bf16 in, f32 out) ----------------
__global__ __launch_bounds__(256) void reduce_tf_kernel(const ushort* __restrict__ hid, float* __restrict__ tf){
  int bt = blockIdx.x, tid = threadIdx.x;
  for (int d = tid; d < 512; d += 256){
    float s = 0.f;
    for (int n = 0; n < 64; n++) s += bf2f(hid[((size_t)bt*64 + n)*512 + d]);
    tf[(size_t)bt*512 + d] = s * (1.f/64.f);
  }
}

// ---------------- heads ----------------
__global__ __launch_bounds__(256) void head_kernel(
    const float* __restrict__ tf,
    const float* __restrict__ th_w1, const float* __restrict__ th_b1,
    const float* __restrict__ th_w2, const float* __restrict__ th_b2,
    const float* __restrict__ sh_w1, const float* __restrict__ sh_b1,
    const float* __restrict__ sh_w2, const float* __restrict__ sh_b2,
    const float* __restrict__ pf_w1, const float* __restrict__ pf_b1,
    const float* __restrict__ pf_w2, const float* __restrict__ pf_b2,
    float* __restrict__ out)
{
  __shared__ float z[512];
  __shared__ float red[4];
  int bi = blockIdx.x, tid = threadIdx.x;
  const float *w1, *b1, *w2, *b2;
  float* dst;
  if (bi < 64){
    w1 = pf_w1; b1 = pf_b1; w2 = pf_w2; b2 = pf_b2; dst = out + 4 + bi;
    z[tid]       = tf[(size_t)bi*512 + tid];
    z[tid + 256] = tf[(size_t)bi*512 + tid + 256];
  } else if (bi < 66){
    int b = bi - 64;
    w1 = th_w1; b1 = th_b1; w2 = th_w2; b2 = th_b2; dst = out + b;
    z[tid]       = tf[(size_t)(b*32 + 31)*512 + tid];
    z[tid + 256] = tf[(size_t)(b*32 + 31)*512 + tid + 256];
  } else {
    int b = bi - 66;
    w1 = sh_w1; b1 = sh_b1; w2 = sh_w2; b2 = sh_b2; dst = out + 2 + b;
    float s0 = 0.f, s1 = 0.f;
    for (int t = 0; t < 32; t++){
      s0 += tf[(size_t)(b*32 + t)*512 + tid];
      s1 += tf[(size_t)(b*32 + t)*512 + tid + 256];
    }
    z[tid] = s0 * (1.f/32.f); z[tid + 256] = s1 * (1.f/32.f);
  }
  __syncthreads();
  float a = b1[tid];
  const float* wrow = w1 + (size_t)tid * 512;
  for (int k = 0; k < 512; k++) a = fmaf(wrow[k], z[k], a);
  a = (a > 0.f) ? a : 0.2f * a;
  float s = blockReduceSum(a * w2[tid], red);
  if (tid == 0) *dst = s + b2[0];
}

__global__ __launch_bounds__(64) void final_kernel(float* __restrict__ out){
  int b = threadIdx.x;
  if (b < 2){
    float s = 0.f;
    for (int t = 0; t < 32; t++) s += out[4 + b*32 + t];
    out[68 + b] = out[b] + out[2 + b] + s * (1.f/32.f);
  }
}

extern "C" void kernel_launch(void* const* d_in, const int* in_sizes, int n_in,
                              void* d_out, int out_size, void* d_ws, size_t ws_size,
                              hipStream_t stream)
{
  const float* x          = (const float*)d_in[0];
  const float* patch_w    = (const float*)d_in[1];
  const float* patch_b    = (const float*)d_in[2];
  const float* tok_ln_g   = (const float*)d_in[3];
  const float* tok_ln_b   = (const float*)d_in[4];
  const float* spatial_pos= (const float*)d_in[5];
  const float* temporal_pos=(const float*)d_in[6];
  const float* snorm_g    = (const float*)d_in[7];
  const float* snorm_b    = (const float*)d_in[8];
  const float* sa_in_w    = (const float*)d_in[9];
  const float* sa_in_b    = (const float*)d_in[10];
  const float* sa_out_w   = (const float*)d_in[11];
  const float* sa_out_b   = (const float*)d_in[12];
  const float* ln1_g      = (const float*)d_in[13];
  const float* ln1_b      = (const float*)d_in[14];
  const float* kqv_w      = (const float*)d_in[15];
  const float* kqv_b      = (const float*)d_in[16];
  const float* proj_w     = (const float*)d_in[17];
  const float* proj_b     = (const float*)d_in[18];
  const float* ln2_g      = (const float*)d_in[19];
  const float* ln2_b      = (const float*)d_in[20];
  const float* fc_w       = (const float*)d_in[21];
  const float* fc_b       = (const float*)d_in[22];
  const float* cproj_w    = (const float*)d_in[23];
  const float* cproj_b    = (const float*)d_in[24];
  const float* lnf_g      = (const float*)d_in[25];
  const float* lnf_b      = (const float*)d_in[26];
  const float* th_w1 = (const float*)d_in[27];
  const float* th_b1 = (const float*)d_in[28];
  const float* th_w2 = (const float*)d_in[29];
  const float* th_b2 = (const float*)d_in[30];
  const float* sh_w1 = (const float*)d_in[31];
  const float* sh_b1 = (const float*)d_in[32];
  const float* sh_w2 = (const float*)d_in[33];
  const float* sh_b2 = (const float*)d_in[34];
  const float* pf_w1 = (const float*)d_in[35];
  const float* pf_b1 = (const float*)d_in[36];
  const float* pf_w2 = (const float*)d_in[37];
  const float* pf_b2 = (const float*)d_in[38];

  float* out = (float*)d_out;
  // workspace layout (bytes)
  char* p = (char*)d_ws;
  float*  A  = (float*)p;      p += (size_t)MTOK*512*4;    // f32 hidden
  ushort* Ru = (ushort*)p;     p += (size_t)MTOK*2048*2;   // bf16 qkv/gelu; f32 patch-gemm out
  ushort* Bf = (ushort*)p;     p += (size_t)MTOK*512*2;    // ln out bf16
  ushort* Ef = (ushort*)p;     p += (size_t)MTOK*512*2;    // attn out bf16 (also im2col patches)
  float*  tfp = (float*)p;     p += (size_t)64*512*4;
  ushort* OpB = (ushort*)p;    p += (size_t)2*MTOK*512*2;  // kv-split partial O (2 halves)
  float*  mlB = (float*)p;     p += (size_t)2*MTOK*8*2*4;  // kv-split (m,l)
  ushort* Wslot = (ushort*)p;  p += (size_t)1048576*2;     // fallback weight slot
  ushort* Wall = (ushort*)p;   p += (size_t)W_TOTAL*2;     // upfront bf16 arena
  const size_t NEED_BIG = (size_t)(p - (char*)d_ws);
  float*  Pf = (float*)Ru;     // patch gemm f32 out 4096x512
  ushort* Pm = Ef;             // patches bf16 4096x192 (before Ef first written)

  const bool big = (ws_size >= NEED_BIG);

  if (big){
    cvt_all_kernel<<<10800, 256, 0, stream>>>(patch_w, sa_in_w, sa_out_w, kqv_w,
                                              proj_w, fc_w, cproj_w, Wall);
  }
  auto W = [&](const float* src, size_t arena_off, size_t nelem) -> const ushort* {
    if (big) return Wall + arena_off;
    cvt_w_kernel<<<(int)(nelem/2048), 256, 0, stream>>>(src, Wslot, (int)nelem);
    return Wslot;
  };

  // patch embed: im2col -> MFMA GEMM -> LN+pos
  im2col_kernel<<<384, 256, 0, stream>>>(x, Pm);
  gemm2_kernel<64,64,false,false,false><<<dim3(8, 64), 256, 0, stream>>>(
      Pm, W(patch_w, OFF_PATCH, 512*192), patch_b, nullptr, Pf, MTOK, 512, 192);
  ln_pos_kernel<<<1024, 256, 0, stream>>>(Pf, A, tok_ln_g, tok_ln_b, spatial_pos, temporal_pos);

  // spatial layers
  for (int i = 0; i < 3; i++){
    ln_bf16_kernel<<<1024, 256, 0, stream>>>(A, Bf, snorm_g, snorm_b);
    gemm2_kernel<64,128,false,true,false><<<dim3(12, 64), 256, 0, stream>>>(
        Bf, W(sa_in_w + (size_t)i*1536*512, OFF_SAIN + (size_t)i*786432, 1536*512),
        sa_in_b + (size_t)i*1536, nullptr, Ru, MTOK, 1536, 512);
    spatial_attn_mfma_kernel<<<dim3(64, 4), 256, 0, stream>>>(Ru, Ef);
    gemm2_kernel<64,64,false,false,false><<<dim3(8, 64), 256, 0, stream>>>(
        Ef, W(sa_out_w + (size_t)i*512*512, OFF_SAOUT + (size_t)i*262144, 512*512),
        sa_out_b + (size_t)i*512, A, A, MTOK, 512, 512);
  }
  // temporal layers (kv-split flash + merge)
  for (int i = 0; i < 6; i++){
    ln_bf16_kernel<<<1024, 256, 0, stream>>>(A, Bf, ln1_g + (size_t)i*512, ln1_b + (size_t)i*512);
    gemm2_kernel<64,128,false,true,false><<<dim3(12, 64), 256, 0, stream>>>(
        Bf, W(kqv_w + (size_t)i*1536*512, OFF_KQV + (size_t)i*786432, 1536*512),
        kqv_b + (size_t)i*1536, nullptr, Ru, MTOK, 1536, 512);
    temporal_attn_split_kernel<<<1024, 256, 0, stream>>>(Ru, OpB, mlB);
    attn_merge_kernel<<<1024, 256, 0, stream>>>(OpB, mlB, Ef);
    gemm2_kernel<64,64,false,false,false><<<dim3(8, 64), 256, 0, stream>>>(
        Ef, W(proj_w + (size_t)i*512*512, OFF_PROJ + (size_t)i*262144, 512*512),
        proj_b + (size_t)i*512, A, A, MTOK, 512, 512);
    ln_bf16_kernel<<<1024, 256, 0, stream>>>(A, Bf, ln2_g + (size_t)i*512, ln2_b + (size_t)i*512);
    gemm2_kernel<64,128,true,true,true><<<dim3(16, 64), 256, 0, stream>>>(
        Bf, W(fc_w + (size_t)i*2048*512, OFF_FC + (size_t)i*1048576, 2048*512),
        fc_b + (size_t)i*2048, nullptr, Ru, MTOK, 2048, 512);
    gemm2_kernel<64,64,false,false,false><<<dim3(8, 64), 256, 0, stream>>>(
        Ru, W(cproj_w + (size_t)i*512*2048, OFF_CPROJ + (size_t)i*1048576, 512*2048),
        cproj_b + (size_t)i*512, A, A, MTOK, 512, 2048);
  }
  // final LN + heads
  ln_bf16_kernel<<<1024, 256, 0, stream>>>(A, Bf, lnf_g, lnf_b);
  reduce_tf_kernel<<<64, 256, 0, stream>>>(Bf, tfp);
  head_kernel<<<68, 256, 0, stream>>>(tfp, th_w1, th_b1, th_w2, th_b2,
                                      sh_w1, sh_b1, sh_w2, sh_b2,
                                      pf_w1, pf_b1, pf_w2, pf_b2, out);
  final_kernel<<<1, 64, 0, stream>>>(out);
}

// Round 16
// 767.383 us; speedup vs baseline: 1.1118x; 1.0464x over previous
//
#include <hip/hip_runtime.h>
#include <hip/hip_bf16.h>
#include <math.h>

// Sizes: B=2 T=32 C=3 H=W=64 P=8 -> N=64, D=512, L=2048, M=B*T*N=4096
#define MTOK 4096

typedef __bf16 bf16x8 __attribute__((ext_vector_type(8)));
typedef float f32x4 __attribute__((ext_vector_type(4)));

__device__ __forceinline__ ushort f2bf(float f){
  __hip_bfloat16 h = __float2bfloat16(f);
  return *reinterpret_cast<ushort*>(&h);
}
__device__ __forceinline__ float bf2f(ushort u){
  return __uint_as_float(((uint)u) << 16);
}
__device__ __forceinline__ void gload_lds16(const void* g, void* l){
  __builtin_amdgcn_global_load_lds((__attribute__((address_space(1))) void*)(void*)g,
                                   (__attribute__((address_space(3))) void*)l, 16, 0, 0);
}

__device__ __forceinline__ float blockReduceSum(float v, float* red){
  #pragma unroll
  for (int off = 32; off; off >>= 1) v += __shfl_down(v, off, 64);
  int lane = threadIdx.x & 63, wid = threadIdx.x >> 6;
  __syncthreads();
  if (lane == 0) red[wid] = v;
  __syncthreads();
  float r = 0.f;
  int nw = blockDim.x >> 6;
  for (int i = 0; i < nw; i++) r += red[i];
  return r;
}
__device__ __forceinline__ float rowMax16(float v){
  #pragma unroll
  for (int m = 8; m; m >>= 1) v = fmaxf(v, __shfl_xor(v, m, 64));
  return v;
}
__device__ __forceinline__ float rowSum16(float v){
  #pragma unroll
  for (int m = 8; m; m >>= 1) v += __shfl_xor(v, m, 64);
  return v;
}

// ---------------- weight f32 -> bf16 (per-matrix fallback) ----------------
__global__ __launch_bounds__(256) void cvt_w_kernel(
    const float* __restrict__ src, ushort* __restrict__ dst, int n)
{
  int i = (blockIdx.x * 256 + threadIdx.x) * 8;
  float4 a = *(const float4*)(src + i);
  float4 b = *(const float4*)(src + i + 4);
  uint4 o;
  o.x = (uint)f2bf(a.x) | ((uint)f2bf(a.y) << 16);
  o.y = (uint)f2bf(a.z) | ((uint)f2bf(a.w) << 16);
  o.z = (uint)f2bf(b.x) | ((uint)f2bf(b.y) << 16);
  o.w = (uint)f2bf(b.z) | ((uint)f2bf(b.w) << 16);
  *(uint4*)(dst + i) = o;
}

// ---------------- all weights -> bf16 arena (one dispatch) ----------------
#define OFF_PATCH 0u
#define OFF_SAIN  98304u
#define OFF_SAOUT 2457600u
#define OFF_KQV   3244032u
#define OFF_PROJ  7962624u
#define OFF_FC    9535488u
#define OFF_CPROJ 15826944u
#define W_TOTAL   22118400u
__global__ __launch_bounds__(256) void cvt_all_kernel(
    const float* __restrict__ pw, const float* __restrict__ sain,
    const float* __restrict__ saout, const float* __restrict__ kqv,
    const float* __restrict__ proj, const float* __restrict__ fc,
    const float* __restrict__ cproj, ushort* __restrict__ dst)
{
  int blk = blockIdx.x;
  const float* src; size_t off;
  if      (blk <    48){ src = pw;    off = OFF_PATCH; }
  else if (blk <  1200){ src = sain;  off = OFF_SAIN;  blk -= 48;   }
  else if (blk <  1584){ src = saout; off = OFF_SAOUT; blk -= 1200; }
  else if (blk <  3888){ src = kqv;   off = OFF_KQV;   blk -= 1584; }
  else if (blk <  4656){ src = proj;  off = OFF_PROJ;  blk -= 3888; }
  else if (blk <  7728){ src = fc;    off = OFF_FC;    blk -= 4656; }
  else                 { src = cproj; off = OFF_CPROJ; blk -= 7728; }
  size_t si = (size_t)blk*2048 + threadIdx.x*8;
  float4 a = *(const float4*)(src + si);
  float4 b = *(const float4*)(src + si + 4);
  uint4 o;
  o.x = (uint)f2bf(a.x) | ((uint)f2bf(a.y) << 16);
  o.y = (uint)f2bf(a.z) | ((uint)f2bf(a.w) << 16);
  o.z = (uint)f2bf(b.x) | ((uint)f2bf(b.y) << 16);
  o.w = (uint)f2bf(b.z) | ((uint)f2bf(b.w) << 16);
  *(uint4*)(dst + off + si) = o;
}

// ---------------- im2col: x -> patches [4096][192] bf16 ----------------
__global__ __launch_bounds__(256) void im2col_kernel(
    const float* __restrict__ x, ushort* __restrict__ Pm)
{
  int idx = blockIdx.x*256 + threadIdx.x;   // 0..98303
  int m = idx / 24, e8 = idx % 24;
  int b = m >> 11, t = (m >> 6) & 31, n = m & 63;
  int hn = n >> 3, wn = n & 7;
  int c = e8 >> 3, ph = e8 & 7;
  const float* src = x + (((size_t)(b*32 + t)*3 + c)*64 + hn*8 + ph)*64 + wn*8;
  float4 a = *(const float4*)src;
  float4 bq = *(const float4*)(src + 4);
  uint4 o;
  o.x = (uint)f2bf(a.x) | ((uint)f2bf(a.y) << 16);
  o.y = (uint)f2bf(a.z) | ((uint)f2bf(a.w) << 16);
  o.z = (uint)f2bf(bq.x) | ((uint)f2bf(bq.y) << 16);
  o.w = (uint)f2bf(bq.z) | ((uint)f2bf(bq.w) << 16);
  *(uint4*)(Pm + (size_t)m*192 + e8*8) = o;
}

// ---------------- tok LN + pos (wave per row, 4 rows/block) ----------------
__global__ __launch_bounds__(256) void ln_pos_kernel(
    const float* __restrict__ in, float* __restrict__ out,
    const float* __restrict__ g, const float* __restrict__ b,
    const float* __restrict__ spos, const float* __restrict__ tpos)
{
  int r = blockIdx.x*4 + (threadIdx.x >> 6);
  int lane = threadIdx.x & 63;
  int n = r & 63, t = (r >> 6) & 31;
  const float* row = in + (size_t)r*512 + lane*8;
  float4 v0 = *(const float4*)row;
  float4 v1 = *(const float4*)(row + 4);
  float s = v0.x+v0.y+v0.z+v0.w+v1.x+v1.y+v1.z+v1.w;
  float q = v0.x*v0.x+v0.y*v0.y+v0.z*v0.z+v0.w*v0.w+v1.x*v1.x+v1.y*v1.y+v1.z*v1.z+v1.w*v1.w;
  #pragma unroll
  for (int m = 1; m < 64; m <<= 1){ s += __shfl_xor(s, m, 64); q += __shfl_xor(q, m, 64); }
  float mu = s*(1.f/512.f);
  float inv = rsqrtf(q*(1.f/512.f) - mu*mu + 1e-5f);
  const float* gp = g + lane*8;
  const float* bp = b + lane*8;
  const float* sp = spos + n*512 + lane*8;
  const float* tp = tpos + t*512 + lane*8;
  float* op = out + (size_t)r*512 + lane*8;
  #pragma unroll
  for (int e = 0; e < 2; e++){
    float4 vv = e ? v1 : v0;
    float4 gg = *(const float4*)(gp + e*4);
    float4 bb = *(const float4*)(bp + e*4);
    float4 ss = *(const float4*)(sp + e*4);
    float4 tt = *(const float4*)(tp + e*4);
    float4 oo;
    oo.x = (vv.x-mu)*inv*gg.x + bb.x + ss.x + tt.x;
    oo.y = (vv.y-mu)*inv*gg.y + bb.y + ss.y + tt.y;
    oo.z = (vv.z-mu)*inv*gg.z + bb.z + ss.z + tt.z;
    oo.w = (vv.w-mu)*inv*gg.w + bb.w + ss.w + tt.w;
    *(float4*)(op + e*4) = oo;
  }
}

// ---------------- LayerNorm (D=512) fp32 in -> bf16 out (wave per row) ----------------
__global__ __launch_bounds__(256) void ln_bf16_kernel(
    const float* __restrict__ in, ushort* __restrict__ out,
    const float* __restrict__ g, const float* __restrict__ b)
{
  int r = blockIdx.x*4 + (threadIdx.x >> 6);
  int lane = threadIdx.x & 63;
  const float* row = in + (size_t)r*512 + lane*8;
  float4 v0 = *(const float4*)row;
  float4 v1 = *(const float4*)(row + 4);
  float s = v0.x+v0.y+v0.z+v0.w+v1.x+v1.y+v1.z+v1.w;
  float q = v0.x*v0.x+v0.y*v0.y+v0.z*v0.z+v0.w*v0.w+v1.x*v1.x+v1.y*v1.y+v1.z*v1.z+v1.w*v1.w;
  #pragma unroll
  for (int m = 1; m < 64; m <<= 1){ s += __shfl_xor(s, m, 64); q += __shfl_xor(q, m, 64); }
  float mu = s*(1.f/512.f);
  float inv = rsqrtf(q*(1.f/512.f) - mu*mu + 1e-5f);
  float4 g0 = *(const float4*)(g + lane*8);
  float4 g1 = *(const float4*)(g + lane*8 + 4);
  float4 b0 = *(const float4*)(b + lane*8);
  float4 b1 = *(const float4*)(b + lane*8 + 4);
  uint4 o;
  o.x = (uint)f2bf((v0.x-mu)*inv*g0.x + b0.x) | ((uint)f2bf((v0.y-mu)*inv*g0.y + b0.y) << 16);
  o.y = (uint)f2bf((v0.z-mu)*inv*g0.z + b0.z) | ((uint)f2bf((v0.w-mu)*inv*g0.w + b0.w) << 16);
  o.z = (uint)f2bf((v1.x-mu)*inv*g1.x + b1.x) | ((uint)f2bf((v1.y-mu)*inv*g1.y + b1.y) << 16);
  o.w = (uint)f2bf((v1.z-mu)*inv*g1.z + b1.z) | ((uint)f2bf((v1.w-mu)*inv*g1.w + b1.w) << 16);
  *(uint4*)(out + (size_t)r*512 + lane*8) = o;
}

// ---------------- MFMA GEMM v2 + XCD-aware block swizzle ----------------
// 1-D grid of (Nn/BN)*64 blocks. Physical XCD ~= id&7; each XCD owns an
// 8-row band of M-tiles so X panels stay resident in its private L2:
//   y = (id&7)*8 + (id>>3)/nx ; x = (id>>3)%nx   (bijective; grid%8==0)
// WSB=false: both operands double-buffered, 1 barrier/step.
// WSB=true : X dbuf, W single-buffered (fc: fits 4+ blocks/CU).
template<int BM, int BN, bool GELU, bool BF16OUT, bool WSB>
__global__ __launch_bounds__(256) void gemm2_kernel(
    const ushort* __restrict__ X, const ushort* __restrict__ Wb,
    const float* __restrict__ bias, const float* __restrict__ res,
    void* __restrict__ Yv, int M, int Nn, int K)
{
  constexpr int WROWS = (BN == 128) ? 2 : 4;
  constexpr int WM = BM / WROWS;
  constexpr int FM = WM / 16;
  constexpr int FN = 4;
  constexpr int SMEM = WSB ? (2*BM+BN)*128 : 2*(BM+BN)*128;
  __shared__ __attribute__((aligned(16))) char smem[SMEM];
  int tid = threadIdx.x, lane = tid & 63, wv = tid >> 6;
  int id = blockIdx.x;
  int nx = Nn / BN;
  int xcd = id & 7;
  int k8 = id >> 3;
  int bm = (xcd * 8 + k8 / nx) * BM;
  int bn = (k8 % nx) * BN;
  int wm, wn;
  if (BN == 128){ wm = (wv >> 1) * WM; wn = (wv & 1) * 64; }
  else          { wm = wv * WM;        wn = 0; }

  f32x4 acc[FM][FN];
  #pragma unroll
  for (int i = 0; i < FM; i++)
    #pragma unroll
    for (int j = 0; j < FN; j++){ f32x4 z = {0.f,0.f,0.f,0.f}; acc[i][j] = z; }

  int rowoff = wv*8 + (lane >> 3);
  int colsrc = ((lane & 7) ^ (lane >> 3)) * 16;

  auto stageX = [&](char* Xd, int k0){
    #pragma unroll
    for (int i = 0; i < BM/32; i++){
      int row = i*32 + rowoff;
      gload_lds16((const char*)(X + (size_t)(bm + row)*K + k0) + colsrc,
                  Xd + (i*32 + wv*8)*128);
    }
  };
  auto stageW = [&](char* Wd, int k0){
    #pragma unroll
    for (int i = 0; i < BN/32; i++){
      int row = i*32 + rowoff;
      gload_lds16((const char*)(Wb + (size_t)(bn + row)*K + k0) + colsrc,
                  Wd + (i*32 + wv*8)*128);
    }
  };
  auto compute = [&](const char* Xc, const char* Wc){
    #pragma unroll
    for (int kc = 0; kc < 2; kc++){
      bf16x8 a[FM], b[FN];
      #pragma unroll
      for (int f = 0; f < FM; f++){
        int ra = wm + f*16 + (lane & 15);
        a[f] = *(const bf16x8*)(Xc + ra*128 + ((kc*64 + (lane>>4)*16) ^ ((ra & 7) << 4)));
      }
      #pragma unroll
      for (int f = 0; f < FN; f++){
        int rb = wn + f*16 + (lane & 15);
        b[f] = *(const bf16x8*)(Wc + rb*128 + ((kc*64 + (lane>>4)*16) ^ ((rb & 7) << 4)));
      }
      #pragma unroll
      for (int i = 0; i < FM; i++)
        #pragma unroll
        for (int j = 0; j < FN; j++)
          acc[i][j] = __builtin_amdgcn_mfma_f32_16x16x32_bf16(a[i], b[j], acc[i][j], 0, 0, 0);
    }
  };

  int nt = K >> 6;
  if constexpr (WSB){
    char* Xs0 = smem;
    char* Xs1 = smem + BM*128;
    char* WsS = smem + 2*BM*128;
    stageX(Xs0, 0);
    stageW(WsS, 0);
    __syncthreads();
    for (int t = 0; t < nt; t++){
      char* Xc = (t & 1) ? Xs1 : Xs0;
      if (t + 1 < nt) stageX((t & 1) ? Xs0 : Xs1, (t+1)*64);
      compute(Xc, WsS);
      __syncthreads();                  // X(t+1) landed; W reads done
      if (t + 1 < nt) stageW(WsS, (t+1)*64);
      __syncthreads();                  // W(t+1) drained
    }
  } else {
    char* Xs0 = smem;
    char* Ws0 = smem + BM*128;
    char* Xs1 = smem + (BM+BN)*128;
    char* Ws1 = Xs1 + BM*128;
    stageX(Xs0, 0);
    stageW(Ws0, 0);
    __syncthreads();
    for (int t = 0; t < nt; t++){
      char* Xc = (t & 1) ? Xs1 : Xs0;
      char* Wc = (t & 1) ? Ws1 : Ws0;
      if (t + 1 < nt){
        stageX((t & 1) ? Xs0 : Xs1, (t+1)*64);
        stageW((t & 1) ? Ws0 : Ws1, (t+1)*64);
      }
      compute(Xc, Wc);
      __syncthreads();
    }
  }

  int col0 = lane & 15;
  float bv[FN];
  #pragma unroll
  for (int fn = 0; fn < FN; fn++) bv[fn] = bias[bn + wn + fn*16 + col0];
  #pragma unroll
  for (int fm = 0; fm < FM; fm++){
    #pragma unroll
    for (int r = 0; r < 4; r++){
      int m = bm + wm + fm*16 + (lane >> 4)*4 + r;
      #pragma unroll
      for (int fn = 0; fn < FN; fn++){
        int n = bn + wn + fn*16 + col0;
        float v = acc[fm][fn][r] + bv[fn];
        if (res) v += res[(size_t)m*Nn + n];
        if (GELU) v = 0.5f * v * (1.f + erff(v * 0.70710678118654752440f));
        if (BF16OUT) ((ushort*)Yv)[(size_t)m*Nn + n] = f2bf(v);
        else         ((float*) Yv)[(size_t)m*Nn + n] = v;
      }
    }
  }
}

// ---------------- spatial attention, bf16 MFMA ----------------
__global__ __launch_bounds__(256) void spatial_attn_mfma_kernel(
    const ushort* __restrict__ qkv, ushort* __restrict__ y)
{
  __shared__ __attribute__((aligned(16))) char Ks[64*256];
  __shared__ __attribute__((aligned(16))) char Vt[128*128];
  __shared__ __attribute__((aligned(16))) char Ps[64*128];
  int bt = blockIdx.x, h = blockIdx.y;
  int tid = threadIdx.x, lane = tid & 63, w = tid >> 6;
  const ushort* base = qkv + (size_t)bt*64*1536 + (size_t)h*128;
  const float scale = 0.08838834764831845f;

  int qrow = w*16 + (lane & 15);
  bf16x8 qa[4];
  #pragma unroll
  for (int kc = 0; kc < 4; kc++)
    qa[kc] = *(const bf16x8*)(base + (size_t)qrow*1536 + kc*32 + (lane>>4)*8);

  #pragma unroll
  for (int i = 0; i < 4; i++){
    int row = w*16 + i*4 + (lane >> 4);
    const char* src = (const char*)(base + (size_t)row*1536 + 512) + (((lane & 15) ^ (row & 15)) * 16);
    char* dst = Ks + (w*16 + i*4)*256;
    gload_lds16(src, dst);
  }
  {
    int vj = (tid & 31) * 2;
    int d0 = (tid >> 5) * 16;
    const ushort* v0p = base + (size_t)vj*1536 + 1024 + d0;
    const ushort* v1p = v0p + 1536;
    uint4 a0 = *(const uint4*)(v0p);
    uint4 a1 = *(const uint4*)(v0p + 8);
    uint4 b0 = *(const uint4*)(v1p);
    uint4 b1 = *(const uint4*)(v1p + 8);
    uint av[8] = {a0.x, a0.y, a0.z, a0.w, a1.x, a1.y, a1.z, a1.w};
    uint bv[8] = {b0.x, b0.y, b0.z, b0.w, b1.x, b1.y, b1.z, b1.w};
    int cb = 4 * (tid & 31);
    #pragma unroll
    for (int e = 0; e < 8; e++){
      int dl = d0 + e*2, dh = dl + 1;
      uint vlo = (av[e] & 0xffffu) | ((bv[e] & 0xffffu) << 16);
      uint vhi = (av[e] >> 16) | (bv[e] & 0xffff0000u);
      *(uint*)(Vt + dl*128 + (cb ^ ((dl & 7) << 4))) = vlo;
      *(uint*)(Vt + dh*128 + (cb ^ ((dh & 7) << 4))) = vhi;
    }
  }
  __syncthreads();

  f32x4 zero4 = {0.f,0.f,0.f,0.f};
  f32x4 accS[4];
  __builtin_amdgcn_s_setprio(1);
  #pragma unroll
  for (int jt = 0; jt < 4; jt++){
    accS[jt] = zero4;
    #pragma unroll
    for (int kc = 0; kc < 4; kc++){
      int krow = jt*16 + (lane & 15);
      bf16x8 kb = *(const bf16x8*)(Ks + krow*256 + ((kc*64 + (lane>>4)*16) ^ ((krow & 15) << 4)));
      accS[jt] = __builtin_amdgcn_mfma_f32_16x16x32_bf16(qa[kc], kb, accS[jt], 0, 0, 0);
    }
  }
  __builtin_amdgcn_s_setprio(0);
  float l_sum[4];
  #pragma unroll
  for (int r = 0; r < 4; r++){
    float mx = fmaxf(fmaxf(accS[0][r], accS[1][r]), fmaxf(accS[2][r], accS[3][r]));
    mx = rowMax16(mx);
    int prow = w*16 + (lane>>4)*4 + r;
    int swz = (prow & 7) << 4;
    char* pbase = Ps + prow*128;
    float ps = 0.f;
    #pragma unroll
    for (int jt = 0; jt < 4; jt++){
      float p = __expf((accS[jt][r] - mx) * scale);
      ushort pb = f2bf(p);
      *(ushort*)(pbase + ((2*(jt*16 + (lane & 15))) ^ swz)) = pb;
      ps += bf2f(pb);
    }
    l_sum[r] = rowSum16(ps);
  }
  bf16x8 pa[2];
  #pragma unroll
  for (int kc2 = 0; kc2 < 2; kc2++){
    int prow = w*16 + (lane & 15);
    pa[kc2] = *(const bf16x8*)(Ps + prow*128 + ((kc2*64 + (lane>>4)*16) ^ ((prow & 7) << 4)));
  }
  f32x4 o[8];
  __builtin_amdgcn_s_setprio(1);
  #pragma unroll
  for (int dt = 0; dt < 8; dt++){
    o[dt] = zero4;
    #pragma unroll
    for (int kc2 = 0; kc2 < 2; kc2++){
      int vrow = dt*16 + (lane & 15);
      bf16x8 vb = *(const bf16x8*)(Vt + vrow*128 + ((kc2*64 + (lane>>4)*16) ^ ((vrow & 7) << 4)));
      o[dt] = __builtin_amdgcn_mfma_f32_16x16x32_bf16(pa[kc2], vb, o[dt], 0, 0, 0);
    }
  }
  __builtin_amdgcn_s_setprio(0);
  #pragma unroll
  for (int r = 0; r < 4; r++){
    float invl = 1.f / l_sum[r];
    int token = bt*64 + w*16 + (lane>>4)*4 + r;
    ushort* yrow = y + (size_t)token*512 + h*128;
    #pragma unroll
    for (int dt = 0; dt < 8; dt++)
      yrow[dt*16 + (lane & 15)] = f2bf(o[dt][r] * invl);
  }
}

// ---------------- temporal causal attention: KV-split flash, SWAPPED QK^T + defer-max ----------------
__global__ __launch_bounds__(256) void temporal_attn_split_kernel(
    const ushort* __restrict__ qkv, ushort* __restrict__ Op, float* __restrict__ ml)
{
  __shared__ __attribute__((aligned(16))) char Ks[64*128];
  __shared__ __attribute__((aligned(16))) char Vt[64*128];
  __shared__ __attribute__((aligned(16))) char Ps[4*16*128];
  int id = blockIdx.x;
  int bh = id & 15;
  int rest = id >> 4;
  int qt = 31 - (rest >> 1);
  int half = rest & 1;
  int b = bh >> 3, h = bh & 7;
  int tid = threadIdx.x, lane = tid & 63, w = tid >> 6;
  int g = lane >> 4, q = lane & 15;
  const ushort* base = qkv + (size_t)(b*2048)*1536 + h*64;

  int nk = qt + 1;
  int ktm = (nk + 1) >> 1;
  int kt0 = half ? ktm : 0;
  int kt1 = half ? nk : ktm;

  int qrow = qt*64 + w*16 + q;
  bf16x8 qb[2];
  #pragma unroll
  for (int kc = 0; kc < 2; kc++)
    qb[kc] = *(const bf16x8*)(base + (size_t)qrow*1536 + 512 + kc*32 + g*8);

  f32x4 zero4 = {0.f,0.f,0.f,0.f};
  f32x4 o[4];
  #pragma unroll
  for (int dt = 0; dt < 4; dt++) o[dt] = zero4;
  float m_old = -1e30f, l_sum = 0.f;

  int kcolsrc = ((lane & 7) ^ (lane >> 3)) * 16;
  int vj  = (tid & 31) * 2;
  int vd0 = (tid >> 5) * 8;
  int vcb = 4 * (tid & 31);
  char* myP = Ps + w*2048;
  int pswz = (q & 7) << 4;

  for (int kt = kt0; kt < kt1; kt++){
    __syncthreads();
    #pragma unroll
    for (int i = 0; i < 2; i++){
      int row = w*16 + i*8 + (lane >> 3);
      gload_lds16((const char*)(base + (size_t)(kt*64 + row)*1536) + kcolsrc,
                  Ks + (w*16 + i*8)*128);
    }
    {
      const ushort* v0p = base + (size_t)(kt*64 + vj)*1536 + 1024 + vd0;
      const ushort* v1p = v0p + 1536;
      uint4 a0 = *(const uint4*)v0p;
      uint4 b0 = *(const uint4*)v1p;
      uint av[4] = {a0.x, a0.y, a0.z, a0.w};
      uint bv[4] = {b0.x, b0.y, b0.z, b0.w};
      #pragma unroll
      for (int e = 0; e < 4; e++){
        int dl = vd0 + e*2, dh = dl + 1;
        uint vlo = (av[e] & 0xffffu) | ((bv[e] & 0xffffu) << 16);
        uint vhi = (av[e] >> 16) | (bv[e] & 0xffff0000u);
        *(uint*)(Vt + dl*128 + (vcb ^ ((dl & 7) << 4))) = vlo;
        *(uint*)(Vt + dh*128 + (vcb ^ ((dh & 7) << 4))) = vhi;
      }
    }
    __syncthreads();

    f32x4 accS[4];
    __builtin_amdgcn_s_setprio(1);
    #pragma unroll
    for (int jt = 0; jt < 4; jt++){
      accS[jt] = zero4;
      #pragma unroll
      for (int kc = 0; kc < 2; kc++){
        int krow = jt*16 + q;
        bf16x8 kb = *(const bf16x8*)(Ks + krow*128 + ((kc*64 + g*16) ^ ((krow & 7) << 4)));
        accS[jt] = __builtin_amdgcn_mfma_f32_16x16x32_bf16(kb, qb[kc], accS[jt], 0, 0, 0);
      }
    }
    __builtin_amdgcn_s_setprio(0);
    if (kt == qt){
      int gi = qt*64 + w*16 + q;
      #pragma unroll
      for (int jt = 0; jt < 4; jt++)
        #pragma unroll
        for (int r = 0; r < 4; r++){
          int gj = kt*64 + jt*16 + g*4 + r;
          if (gj > gi) accS[jt][r] = -1e30f;
        }
    }
    float mloc = fmaxf(fmaxf(accS[0][0], accS[0][1]), fmaxf(accS[0][2], accS[0][3]));
    #pragma unroll
    for (int jt = 1; jt < 4; jt++){
      float t2 = fmaxf(fmaxf(accS[jt][0], accS[jt][1]), fmaxf(accS[jt][2], accS[jt][3]));
      mloc = fmaxf(mloc, t2);
    }
    mloc *= 0.125f;
    mloc = fmaxf(mloc, __shfl_xor(mloc, 16, 64));
    mloc = fmaxf(mloc, __shfl_xor(mloc, 32, 64));
    if (!__all(mloc <= m_old + 8.f)){
      float mnew = fmaxf(m_old, mloc);
      float corr = __expf(m_old - mnew);
      l_sum *= corr;
      #pragma unroll
      for (int dt = 0; dt < 4; dt++) o[dt] *= corr;
      m_old = mnew;
    }
    float ps = 0.f;
    #pragma unroll
    for (int jt = 0; jt < 4; jt++){
      ushort pb0 = f2bf(__expf(accS[jt][0]*0.125f - m_old));
      ushort pb1 = f2bf(__expf(accS[jt][1]*0.125f - m_old));
      ushort pb2 = f2bf(__expf(accS[jt][2]*0.125f - m_old));
      ushort pb3 = f2bf(__expf(accS[jt][3]*0.125f - m_old));
      ps += bf2f(pb0) + bf2f(pb1) + bf2f(pb2) + bf2f(pb3);
      uint2 wv;
      wv.x = (uint)pb0 | ((uint)pb1 << 16);
      wv.y = (uint)pb2 | ((uint)pb3 << 16);
      *(uint2*)(myP + q*128 + ((jt*32 + g*8) ^ pswz)) = wv;
    }
    l_sum += ps;

    bf16x8 pfr[2];
    #pragma unroll
    for (int kc2 = 0; kc2 < 2; kc2++)
      pfr[kc2] = *(const bf16x8*)(myP + q*128 + ((kc2*64 + g*16) ^ pswz));
    __builtin_amdgcn_s_setprio(1);
    #pragma unroll
    for (int dt = 0; dt < 4; dt++){
      #pragma unroll
      for (int kc2 = 0; kc2 < 2; kc2++){
        int vrow = dt*16 + q;
        bf16x8 vb = *(const bf16x8*)(Vt + vrow*128 + ((kc2*64 + g*16) ^ ((vrow & 7) << 4)));
        o[dt] = __builtin_amdgcn_mfma_f32_16x16x32_bf16(vb, pfr[kc2], o[dt], 0, 0, 0);
      }
    }
    __builtin_amdgcn_s_setprio(0);
  }
  l_sum += __shfl_xor(l_sum, 16, 64);
  l_sum += __shfl_xor(l_sum, 32, 64);
  size_t tokbase = (size_t)half*4096 + (size_t)b*2048;
  int token = qt*64 + w*16 + q;
  ushort* yrow = Op + (tokbase + token)*512 + h*64;
  #pragma unroll
  for (int dt = 0; dt < 4; dt++){
    ushort4 o4;
    o4.x = f2bf(o[dt][0]); o4.y = f2bf(o[dt][1]);
    o4.z = f2bf(o[dt][2]); o4.w = f2bf(o[dt][3]);
    *(ushort4*)(yrow + dt*16 + g*4) = o4;
  }
  if (g == 0){
    float* mlp = ml + ((tokbase + token)*8 + h)*2;
    mlp[0] = m_old;
    mlp[1] = l_sum;
  }
}

// ---------------- merge the two KV-split halves -> bf16 attn out ----------------
__global__ __launch_bounds__(256) void attn_merge_kernel(
    const ushort* __restrict__ Op, const float* __restrict__ ml, ushort* __restrict__ Ef)
{
  int tok = blockIdx.x*4 + (threadIdx.x >> 6);
  int l6 = threadIdx.x & 63;
  int h = l6 >> 3, d0 = (l6 & 7)*8;
  int e = h*64 + d0;
  const float* m1p = ml + ((size_t)tok*8 + h)*2;
  const float* m2p = ml + (((size_t)4096 + tok)*8 + h)*2;
  float m1 = m1p[0], l1 = m1p[1];
  float m2 = m2p[0], l2 = m2p[1];
  float mm = fmaxf(m1, m2);
  float w1 = __expf(m1 - mm), w2 = __expf(m2 - mm);
  float inv = 1.f / (w1*l1 + w2*l2);
  uint4 a = *(const uint4*)(Op + (size_t)tok*512 + e);
  uint4 bq = *(const uint4*)(Op + ((size_t)4096 + tok)*512 + e);
  uint av[4] = {a.x, a.y, a.z, a.w};
  uint bv[4] = {bq.x, bq.y, bq.z, bq.w};
  uint ov[4];
  #pragma unroll
  for (int p = 0; p < 4; p++){
    float x0 = (w1*bf2f((ushort)(av[p] & 0xffff)) + w2*bf2f((ushort)(bv[p] & 0xffff))) * inv;
    float x1 = (w1*bf2f((ushort)(av[p] >> 16))    + w2*bf2f((ushort)(bv[p] >> 16)))    * inv;
    ov[p] = (uint)f2bf(x0) | ((uint)f2bf(x1) << 16);
  }
  uint4 o; o.x = ov[0]; o.y = ov[1]; o.z = ov[2]; o.w = ov[3];
  *(uint4*)(Ef + (size_t)tok*512 + e) = o;
}

// ---------------- tf = mean over N of lnf(hid) (bf16 in, f32 out) ----------------
__global__ __launch_bounds__(256) void reduce_tf_kernel(const ushort* __restrict__ hid, float* __restrict__ tf){
  int bt = blockIdx.x, tid = threadIdx.x;
  for (int d = tid; d < 512; d += 256){
    float s = 0.f;
    for (int n = 0; n < 64; n++) s += bf2f(hid[((size_t)bt*64 + n)*512 + d]);
    tf[(size_t)bt*512 + d] = s * (1.f/64.f);
  }
}

// ---------------- heads ----------------
__global__ __launch_bounds__(256) void head_kernel(
    const float* __restrict__ tf,
    const float* __restrict__ th_w1, const float* __restrict__ th_b1,
    const float* __restrict__ th_w2, const float* __restrict__ th_b2,
    const float* __restrict__ sh_w1, const float* __restrict__ sh_b1,
    const float* __restrict__ sh_w2, const float* __restrict__ sh_b2,
    const float* __restrict__ pf_w1, const float* __restrict__ pf_b1,
    const float* __restrict__ pf_w2, const float* __restrict__ pf_b2,
    float* __restrict__ out)
{
  __shared__ float z[512];
  __shared__ float red[4];
  int bi = blockIdx.x, tid = threadIdx.x;
  const float *w1, *b1, *w2, *b2;
  float* dst;
  if (bi < 64){
    w1 = pf_w1; b1 = pf_b1; w2 = pf_w2; b2 = pf_b2; dst = out + 4 + bi;
    z[tid]       = tf[(size_t)bi*512 + tid];
    z[tid + 256] = tf[(size_t)bi*512 + tid + 256];
  } else if (bi < 66){
    int b = bi - 64;
    w1 = th_w1; b1 = th_b1; w2 = th_w2; b2 = th_b2; dst = out + b;
    z[tid]       = tf[(size_t)(b*32 + 31)*512 + tid];
    z[tid + 256] = tf[(size_t)(b*32 + 31)*512 + tid + 256];
  } else {
    int b = bi - 66;
    w1 = sh_w1; b1 = sh_b1; w2 = sh_w2; b2 = sh_b2; dst = out + 2 + b;
    float s0 = 0.f, s1 = 0.f;
    for (int t = 0; t < 32; t++){
      s0 += tf[(size_t)(b*32 + t)*512 + tid];
      s1 += tf[(size_t)(b*32 + t)*512 + tid + 256];
    }
    z[tid] = s0 * (1.f/32.f); z[tid + 256] = s1 * (1.f/32.f);
  }
  __syncthreads();
  float a = b1[tid];
  const float* wrow = w1 + (size_t)tid * 512;
  for (int k = 0; k < 512; k++) a = fmaf(wrow[k], z[k], a);
  a = (a > 0.f) ? a : 0.2f * a;
  float s = blockReduceSum(a * w2[tid], red);
  if (tid == 0) *dst = s + b2[0];
}

__global__ __launch_bounds__(64) void final_kernel(float* __restrict__ out){
  int b = threadIdx.x;
  if (b < 2){
    float s = 0.f;
    for (int t = 0; t < 32; t++) s += out[4 + b*32 + t];
    out[68 + b] = out[b] + out[2 + b] + s * (1.f/32.f);
  }
}

extern "C" void kernel_launch(void* const* d_in, const int* in_sizes, int n_in,
                              void* d_out, int out_size, void* d_ws, size_t ws_size,
                              hipStream_t stream)
{
  const float* x          = (const float*)d_in[0];
  const float* patch_w    = (const float*)d_in[1];
  const float* patch_b    = (const float*)d_in[2];
  const float* tok_ln_g   = (const float*)d_in[3];
  const float* tok_ln_b   = (const float*)d_in[4];
  const float* spatial_pos= (const float*)d_in[5];
  const float* temporal_pos=(const float*)d_in[6];
  const float* snorm_g    = (const float*)d_in[7];
  const float* snorm_b    = (const float*)d_in[8];
  const float* sa_in_w    = (const float*)d_in[9];
  const float* sa_in_b    = (const float*)d_in[10];
  const float* sa_out_w   = (const float*)d_in[11];
  const float* sa_out_b   = (const float*)d_in[12];
  const float* ln1_g      = (const float*)d_in[13];
  const float* ln1_b      = (const float*)d_in[14];
  const float* kqv_w      = (const float*)d_in[15];
  const float* kqv_b      = (const float*)d_in[16];
  const float* proj_w     = (const float*)d_in[17];
  const float* proj_b     = (const float*)d_in[18];
  const float* ln2_g      = (const float*)d_in[19];
  const float* ln2_b      = (const float*)d_in[20];
  const float* fc_w       = (const float*)d_in[21];
  const float* fc_b       = (const float*)d_in[22];
  const float* cproj_w    = (const float*)d_in[23];
  const float* cproj_b    = (const float*)d_in[24];
  const float* lnf_g      = (const float*)d_in[25];
  const float* lnf_b      = (const float*)d_in[26];
  const float* th_w1 = (const float*)d_in[27];
  const float* th_b1 = (const float*)d_in[28];
  const float* th_w2 = (const float*)d_in[29];
  const float* th_b2 = (const float*)d_in[30];
  const float* sh_w1 = (const float*)d_in[31];
  const float* sh_b1 = (const float*)d_in[32];
  const float* sh_w2 = (const float*)d_in[33];
  const float* sh_b2 = (const float*)d_in[34];
  const float* pf_w1 = (const float*)d_in[35];
  const float* pf_b1 = (const float*)d_in[36];
  const float* pf_w2 = (const float*)d_in[37];
  const float* pf_b2 = (const float*)d_in[38];

  float* out = (float*)d_out;
  // workspace layout (bytes)
  char* p = (char*)d_ws;
  float*  A  = (float*)p;      p += (size_t)MTOK*512*4;    // f32 hidden
  ushort* Ru = (ushort*)p;     p += (size_t)MTOK*2048*2;   // bf16 qkv/gelu; f32 patch-gemm out
  ushort* Bf = (ushort*)p;     p += (size_t)MTOK*512*2;    // ln out bf16
  ushort* Ef = (ushort*)p;     p += (size_t)MTOK*512*2;    // attn out bf16 (also im2col patches)
  float*  tfp = (float*)p;     p += (size_t)64*512*4;
  ushort* OpB = (ushort*)p;    p += (size_t)2*MTOK*512*2;  // kv-split partial O (2 halves)
  float*  mlB = (float*)p;     p += (size_t)2*MTOK*8*2*4;  // kv-split (m,l)
  ushort* Wslot = (ushort*)p;  p += (size_t)1048576*2;     // fallback weight slot
  ushort* Wall = (ushort*)p;   p += (size_t)W_TOTAL*2;     // upfront bf16 arena
  const size_t NEED_BIG = (size_t)(p - (char*)d_ws);
  float*  Pf = (float*)Ru;     // patch gemm f32 out 4096x512
  ushort* Pm = Ef;             // patches bf16 4096x192 (before Ef first written)

  const bool big = (ws_size >= NEED_BIG);

  if (big){
    cvt_all_kernel<<<10800, 256, 0, stream>>>(patch_w, sa_in_w, sa_out_w, kqv_w,
                                              proj_w, fc_w, cproj_w, Wall);
  }
  auto W = [&](const float* src, size_t arena_off, size_t nelem) -> const ushort* {
    if (big) return Wall + arena_off;
    cvt_w_kernel<<<(int)(nelem/2048), 256, 0, stream>>>(src, Wslot, (int)nelem);
    return Wslot;
  };

  // patch embed: im2col -> MFMA GEMM -> LN+pos
  im2col_kernel<<<384, 256, 0, stream>>>(x, Pm);
  gemm2_kernel<64,64,false,false,false><<<512, 256, 0, stream>>>(
      Pm, W(patch_w, OFF_PATCH, 512*192), patch_b, nullptr, Pf, MTOK, 512, 192);
  ln_pos_kernel<<<1024, 256, 0, stream>>>(Pf, A, tok_ln_g, tok_ln_b, spatial_pos, temporal_pos);

  // spatial layers
  for (int i = 0; i < 3; i++){
    ln_bf16_kernel<<<1024, 256, 0, stream>>>(A, Bf, snorm_g, snorm_b);
    gemm2_kernel<64,128,false,true,false><<<768, 256, 0, stream>>>(
        Bf, W(sa_in_w + (size_t)i*1536*512, OFF_SAIN + (size_t)i*786432, 1536*512),
        sa_in_b + (size_t)i*1536, nullptr, Ru, MTOK, 1536, 512);
    spatial_attn_mfma_kernel<<<dim3(64, 4), 256, 0, stream>>>(Ru, Ef);
    gemm2_kernel<64,64,false,false,false><<<512, 256, 0, stream>>>(
        Ef, W(sa_out_w + (size_t)i*512*512, OFF_SAOUT + (size_t)i*262144, 512*512),
        sa_out_b + (size_t)i*512, A, A, MTOK, 512, 512);
  }
  // temporal layers (kv-split flash + merge)
  for (int i = 0; i < 6; i++){
    ln_bf16_kernel<<<1024, 256, 0, stream>>>(A, Bf, ln1_g + (size_t)i*512, ln1_b + (size_t)i*512);
    gemm2_kernel<64,128,false,true,false><<<768, 256, 0, stream>>>(
        Bf, W(kqv_w + (size_t)i*1536*512, OFF_KQV + (size_t)i*786432, 1536*512),
        kqv_b + (size_t)i*1536, nullptr, Ru, MTOK, 1536, 512);
    temporal_attn_split_kernel<<<1024, 256, 0, stream>>>(Ru, OpB, mlB);
    attn_merge_kernel<<<1024, 256, 0, stream>>>(OpB, mlB, Ef);
    gemm2_kernel<64,64,false,false,false><<<512, 256, 0, stream>>>(
        Ef, W(proj_w + (size_t)i*512*512, OFF_PROJ + (size_t)i*262144, 512*512),
        proj_b + (size_t)i*512, A, A, MTOK, 512, 512);
    ln_bf16_kernel<<<1024, 256, 0, stream>>>(A, Bf, ln2_g + (size_t)i*512, ln2_b + (size_t)i*512);
    gemm2_kernel<64,128,true,true,true><<<1024, 256, 0, stream>>>(
        Bf, W(fc_w + (size_t)i*2048*512, OFF_FC + (size_t)i*1048576, 2048*512),
        fc_b + (size_t)i*2048, nullptr, Ru, MTOK, 2048, 512);
    gemm2_kernel<64,64,false,false,false><<<512, 256, 0, stream>>>(
        Ru, W(cproj_w + (size_t)i*512*2048, OFF_CPROJ + (size_t)i*1048576, 512*2048),
        cproj_b + (size_t)i*512, A, A, MTOK, 512, 2048);
  }
  // final LN + heads
  ln_bf16_kernel<<<1024, 256, 0, stream>>>(A, Bf, lnf_g, lnf_b);
  reduce_tf_kernel<<<64, 256, 0, stream>>>(Bf, tfp);
  head_kernel<<<68, 256, 0, stream>>>(tfp, th_w1, th_b1, th_w2, th_b2,
                                      sh_w1, sh_b1, sh_w2, sh_b2,
                                      pf_w1, pf_b1, pf_w2, pf_b2, out);
  final_kernel<<<1, 64, 0, stream>>>(out);
}